// Round 1
// baseline (842.976 us; speedup 1.0000x reference)
//
#include <hip/hip_runtime.h>
#include <math.h>

#define N_USERS 50000
#define N_ITEMS 50000
#define N_NODES 100000
#define HID     128
#define N_EDGES 1600000

// ---------------- x = concat(user_emb, item_emb) ----------------
__global__ void k_build_x(const float* __restrict__ ue, const float* __restrict__ ie,
                          float* __restrict__ x) {
    const int total = N_NODES * HID / 4;
    const int uquads = N_USERS * HID / 4;
    for (int i = blockIdx.x * blockDim.x + threadIdx.x; i < total; i += gridDim.x * blockDim.x) {
        float4 v = (i < uquads) ? ((const float4*)ue)[i] : ((const float4*)ie)[i - uquads];
        ((float4*)x)[i] = v;
    }
}

// ---------------- degree histogram ----------------
__global__ void k_deg(const int* __restrict__ dst, int* __restrict__ deg) {
    for (int i = blockIdx.x * blockDim.x + threadIdx.x; i < N_EDGES; i += gridDim.x * blockDim.x)
        atomicAdd(&deg[dst[i]], 1);
}

// ---------------- hierarchical exclusive scan ----------------
__global__ void k_scan1(const int* __restrict__ deg, int* __restrict__ rowp,
                        int* __restrict__ partials, float* __restrict__ invd) {
    __shared__ int s[256];
    int t = threadIdx.x;
    int i = blockIdx.x * 256 + t;
    int v = (i < N_NODES) ? deg[i] : 0;
    if (i < N_NODES) invd[i] = 1.0f / (float)max(v, 1);
    s[t] = v;
    __syncthreads();
    for (int off = 1; off < 256; off <<= 1) {
        int add = (t >= off) ? s[t - off] : 0;
        __syncthreads();
        s[t] += add;
        __syncthreads();
    }
    if (i < N_NODES) rowp[i] = s[t] - v;          // block-local exclusive
    if (t == 255) partials[blockIdx.x] = s[255];  // block total
}

__global__ void k_scan2(const int* __restrict__ partials, int* __restrict__ poff, int nparts) {
    __shared__ int s[512];
    int t = threadIdx.x;
    int v = (t < nparts) ? partials[t] : 0;
    s[t] = v;
    __syncthreads();
    for (int off = 1; off < 512; off <<= 1) {
        int add = (t >= off) ? s[t - off] : 0;
        __syncthreads();
        s[t] += add;
        __syncthreads();
    }
    poff[t] = s[t] - v;  // exclusive
}

__global__ void k_scan3(int* __restrict__ rowp, const int* __restrict__ poff,
                        int* __restrict__ wptr) {
    int i = blockIdx.x * 256 + threadIdx.x;
    if (i < N_NODES) {
        int r = rowp[i] + poff[blockIdx.x];
        rowp[i] = r;
        wptr[i] = r;
    }
    if (i == 0) rowp[N_NODES] = N_EDGES;
}

// ---------------- CSR fill ----------------
__global__ void k_fill(const int* __restrict__ src, const int* __restrict__ dst,
                       int* __restrict__ wptr, int* __restrict__ csr) {
    for (int i = blockIdx.x * blockDim.x + threadIdx.x; i < N_EDGES; i += gridDim.x * blockDim.x) {
        int d = dst[i];
        int pos = atomicAdd(&wptr[d], 1);
        csr[pos] = src[i];
    }
}

// ---------------- mean aggregation: one wave per node ----------------
__global__ void k_agg(const float* __restrict__ x, const int* __restrict__ rowp,
                      const int* __restrict__ csr, const float* __restrict__ invd,
                      float* __restrict__ agg) {
    int wave = threadIdx.x >> 6, lane = threadIdx.x & 63;
    int n = blockIdx.x * 4 + wave;
    if (n >= N_NODES) return;
    int e0 = rowp[n], e1 = rowp[n + 1];
    const float2* xp = (const float2*)x;
    float2 acc = make_float2(0.f, 0.f);
    int e = e0;
    for (; e + 1 < e1; e += 2) {
        int s0 = csr[e], s1 = csr[e + 1];
        float2 a = xp[s0 * 64 + lane];
        float2 b = xp[s1 * 64 + lane];
        acc.x += a.x + b.x;
        acc.y += a.y + b.y;
    }
    if (e < e1) {
        int s0 = csr[e];
        float2 a = xp[s0 * 64 + lane];
        acc.x += a.x;
        acc.y += a.y;
    }
    float w = invd[n];
    ((float2*)agg)[n * 64 + lane] = make_float2(acc.x * w, acc.y * w);
}

// ---------------- fused fp32 GEMM: out = A1@W1 + A2@W2 + bias ----------------
// 32 rows x 128 cols per block, 256 threads, 4x4 register tile per thread.
// W staged in LDS in 64-row chunks; A tiles staged once. out may alias A1
// (writes happen after all LDS staging; blocks touch disjoint rows).
__global__ __launch_bounds__(256) void k_gemm(const float* __restrict__ A1,
                                              const float* __restrict__ A2,
                                              const float* __restrict__ W1,
                                              const float* __restrict__ W2,
                                              const float* __restrict__ bias,
                                              float* __restrict__ out) {
    __shared__ float s_a[32 * HID];  // 16 KB
    __shared__ float s_x[32 * HID];  // 16 KB
    __shared__ float s_w[64 * HID];  // 32 KB
    int t = threadIdx.x;
    int row0 = blockIdx.x * 32;

    const float4* a4 = (const float4*)(A1 + (size_t)row0 * HID);
    const float4* x4 = (const float4*)(A2 + (size_t)row0 * HID);
    float4* sa4 = (float4*)s_a;
    float4* sx4 = (float4*)s_x;
#pragma unroll
    for (int i = 0; i < 4; ++i) {
        sa4[t + i * 256] = a4[t + i * 256];
        sx4[t + i * 256] = x4[t + i * 256];
    }

    int jj = t & 31;  // cols 4*jj .. 4*jj+3
    int rr = t >> 5;  // rows 4*rr .. 4*rr+3
    float acc[4][4];
#pragma unroll
    for (int i = 0; i < 4; ++i)
#pragma unroll
        for (int c = 0; c < 4; ++c) acc[i][c] = 0.f;

    const float* Ws[2] = {W1, W2};
#pragma unroll 1
    for (int m = 0; m < 2; ++m) {
        const float* W = Ws[m];
        const float* Smat = (m == 0) ? s_a : s_x;
#pragma unroll 1
        for (int kc = 0; kc < HID; kc += 64) {
            __syncthreads();
            const float4* w4 = (const float4*)(W + kc * HID);
            float4* sw4 = (float4*)s_w;
#pragma unroll
            for (int i = 0; i < 8; ++i) sw4[t + i * 256] = w4[t + i * 256];
            __syncthreads();
#pragma unroll 4
            for (int k4 = 0; k4 < 64; k4 += 4) {
                float4 wv[4];
#pragma unroll
                for (int i = 0; i < 4; ++i)
                    wv[i] = *(const float4*)&s_w[(k4 + i) * HID + 4 * jj];
                float4 av[4];
#pragma unroll
                for (int i = 0; i < 4; ++i)
                    av[i] = *(const float4*)&Smat[(4 * rr + i) * HID + kc + k4];
#pragma unroll
                for (int i = 0; i < 4; ++i) {
                    acc[i][0] += av[i].x * wv[0].x + av[i].y * wv[1].x + av[i].z * wv[2].x + av[i].w * wv[3].x;
                    acc[i][1] += av[i].x * wv[0].y + av[i].y * wv[1].y + av[i].z * wv[2].y + av[i].w * wv[3].y;
                    acc[i][2] += av[i].x * wv[0].z + av[i].y * wv[1].z + av[i].z * wv[2].z + av[i].w * wv[3].z;
                    acc[i][3] += av[i].x * wv[0].w + av[i].y * wv[1].w + av[i].z * wv[2].w + av[i].w * wv[3].w;
                }
            }
        }
    }

    float4 bv = *(const float4*)&bias[4 * jj];
#pragma unroll
    for (int i = 0; i < 4; ++i) {
        float4 o;
        o.x = acc[i][0] + bv.x;
        o.y = acc[i][1] + bv.y;
        o.z = acc[i][2] + bv.z;
        o.w = acc[i][3] + bv.w;
        *(float4*)&out[(size_t)(row0 + 4 * rr + i) * HID + 4 * jj] = o;
    }
}

// ---------------- y[n] = x[n] . W_out + b_out ----------------
__global__ void k_ydot(const float* __restrict__ x, const float* __restrict__ Wout,
                       const float* __restrict__ bout, float* __restrict__ y) {
    int wave = threadIdx.x >> 6, lane = threadIdx.x & 63;
    int n = blockIdx.x * 4 + wave;
    if (n >= N_NODES) return;
    float2 xv = ((const float2*)x)[n * 64 + lane];
    float2 wv = ((const float2*)Wout)[lane];
    float d = xv.x * wv.x + xv.y * wv.y;
#pragma unroll
    for (int off = 32; off; off >>= 1) d += __shfl_down(d, off, 64);
    if (lane == 0) y[n] = d + bout[0];
}

// ---------------- softmax over gathered items ----------------
__device__ inline unsigned fkey(float x) {
    unsigned u = __float_as_uint(x);
    return (u & 0x80000000u) ? ~u : (u | 0x80000000u);
}
__device__ inline float funkey(unsigned k) {
    unsigned u = (k & 0x80000000u) ? (k & 0x7fffffffu) : ~k;
    return __uint_as_float(u);
}

__global__ void k_max(const float* __restrict__ y, const int* __restrict__ item,
                      unsigned* __restrict__ redmax) {
    float m = -3.4e38f;
    for (int i = blockIdx.x * blockDim.x + threadIdx.x; i < N_ITEMS; i += gridDim.x * blockDim.x)
        m = fmaxf(m, y[item[i]]);
#pragma unroll
    for (int off = 32; off; off >>= 1) m = fmaxf(m, __shfl_down(m, off, 64));
    __shared__ float sm[4];
    int lane = threadIdx.x & 63, wave = threadIdx.x >> 6;
    if (lane == 0) sm[wave] = m;
    __syncthreads();
    if (threadIdx.x == 0) {
        float mm = sm[0];
        for (int w = 1; w < 4; ++w) mm = fmaxf(mm, sm[w]);
        atomicMax(redmax, fkey(mm));
    }
}

__global__ void k_sumexp(const float* __restrict__ y, const int* __restrict__ item,
                         const unsigned* __restrict__ redmax, float* __restrict__ redsum) {
    float m = funkey(*redmax);
    float s = 0.f;
    for (int i = blockIdx.x * blockDim.x + threadIdx.x; i < N_ITEMS; i += gridDim.x * blockDim.x)
        s += expf(y[item[i]] - m);
#pragma unroll
    for (int off = 32; off; off >>= 1) s += __shfl_down(s, off, 64);
    __shared__ float sm[4];
    int lane = threadIdx.x & 63, wave = threadIdx.x >> 6;
    if (lane == 0) sm[wave] = s;
    __syncthreads();
    if (threadIdx.x == 0) {
        float ss = sm[0] + sm[1] + sm[2] + sm[3];
        atomicAdd(redsum, ss);
    }
}

__global__ void k_out(const float* __restrict__ y, const int* __restrict__ item,
                      const unsigned* __restrict__ redmax, const float* __restrict__ redsum,
                      const float* __restrict__ dprior, float* __restrict__ out) {
    float m = funkey(*redmax);
    float inv_s = 1.0f / (*redsum);
    float pr = fmaxf(dprior[0], 0.f);
    for (int i = blockIdx.x * blockDim.x + threadIdx.x; i < N_ITEMS; i += gridDim.x * blockDim.x)
        out[i] = pr * expf(y[item[i]] - m) * inv_s;
}

extern "C" void kernel_launch(void* const* d_in, const int* in_sizes, int n_in,
                              void* d_out, int out_size, void* d_ws, size_t ws_size,
                              hipStream_t stream) {
    const int*   item  = (const int*)d_in[0];
    const int*   esrc  = (const int*)d_in[1];
    const int*   edst  = esrc + N_EDGES;
    const float* ue    = (const float*)d_in[2];
    const float* ie    = (const float*)d_in[3];
    const float* Wl1   = (const float*)d_in[4];
    const float* Wr1   = (const float*)d_in[5];
    const float* b1    = (const float*)d_in[6];
    const float* Wl2   = (const float*)d_in[7];
    const float* Wr2   = (const float*)d_in[8];
    const float* b2    = (const float*)d_in[9];
    const float* Wout  = (const float*)d_in[10];
    const float* bout  = (const float*)d_in[11];
    const float* dpri  = (const float*)d_in[12];
    float* out = (float*)d_out;

    // workspace layout (floats/ints), ~110.8 MB total
    float* xA   = (float*)d_ws;                 // 12.8M floats
    float* xB   = xA + (size_t)N_NODES * HID;   // 12.8M floats (agg / layer out)
    int*   deg  = (int*)(xB + (size_t)N_NODES * HID);  // 100000
    float* invd = (float*)(deg + N_NODES);      // 100000
    int*   rowp = (int*)(invd + N_NODES);       // 100001 (pad to 100004)
    int*   wptr = rowp + 100004;                // 100000 (pad to 100004)
    int*   parts = wptr + 100004;               // 512
    int*   poff  = parts + 512;                 // 512
    int*   csr   = poff + 512;                  // 1.6M
    float* y     = (float*)(csr + N_EDGES);     // 100000
    unsigned* redmax = (unsigned*)(y + N_NODES);
    float* redsum = (float*)(redmax + 4);       // keep 16B alignment

    const int SCAN_BLOCKS = (N_NODES + 255) / 256;  // 391

    hipMemsetAsync(deg, 0, N_NODES * sizeof(int), stream);
    hipMemsetAsync(redmax, 0, 32, stream);  // redmax=0 (== key(-inf) floor), redsum=0.f

    k_build_x<<<2048, 256, 0, stream>>>(ue, ie, xA);
    k_deg<<<2048, 256, 0, stream>>>(edst, deg);
    k_scan1<<<SCAN_BLOCKS, 256, 0, stream>>>(deg, rowp, parts, invd);
    k_scan2<<<1, 512, 0, stream>>>(parts, poff, SCAN_BLOCKS);
    k_scan3<<<SCAN_BLOCKS, 256, 0, stream>>>(rowp, poff, wptr);
    k_fill<<<2048, 256, 0, stream>>>(esrc, edst, wptr, csr);

    // layer 1: x = xA ; agg -> xB ; out -> xB (aliases agg, safe)
    k_agg<<<N_NODES / 4, 256, 0, stream>>>(xA, rowp, csr, invd, xB);
    k_gemm<<<N_NODES / 32, 256, 0, stream>>>(xB, xA, Wl1, Wr1, b1, xB);
    // layer 2: x = xB ; agg -> xA ; out -> xA
    k_agg<<<N_NODES / 4, 256, 0, stream>>>(xB, rowp, csr, invd, xA);
    k_gemm<<<N_NODES / 32, 256, 0, stream>>>(xA, xB, Wl2, Wr2, b2, xA);

    k_ydot<<<N_NODES / 4, 256, 0, stream>>>(xA, Wout, bout, y);
    k_max<<<200, 256, 0, stream>>>(y, item, redmax);
    k_sumexp<<<200, 256, 0, stream>>>(y, item, redmax, redsum);
    k_out<<<200, 256, 0, stream>>>(y, item, redmax, redsum, dpri, out);
}

// Round 2
// 573.966 us; speedup vs baseline: 1.4687x; 1.4687x over previous
//
#include <hip/hip_runtime.h>
#include <math.h>

#define N_USERS 50000
#define N_ITEMS 50000
#define N_NODES 100000
#define MPAD    100096   // padded rows: 782 blocks * 128
#define HID     128
#define N_EDGES 1600000

typedef __attribute__((ext_vector_type(8))) short bf16x8;
typedef __attribute__((ext_vector_type(4))) float f32x4;

static __device__ inline ushort f2bf(float f) {
    unsigned u = __float_as_uint(f);
    unsigned r = (u + 0x7fffu + ((u >> 16) & 1u)) >> 16;  // RNE
    return (ushort)r;
}
static __device__ inline float bflo(unsigned v) { return __uint_as_float(v << 16); }
static __device__ inline float bfhi(unsigned v) { return __uint_as_float(v & 0xffff0000u); }

// ---------------- x = concat(user_emb, item_emb) -> bf16 ----------------
__global__ void k_build_x(const float* __restrict__ ue, const float* __restrict__ ie,
                          ushort* __restrict__ x) {
    const int total = N_NODES * HID / 4;   // quads of 4 elements
    const int uquads = N_USERS * HID / 4;
    for (int i = blockIdx.x * blockDim.x + threadIdx.x; i < total; i += gridDim.x * blockDim.x) {
        float4 v = (i < uquads) ? ((const float4*)ue)[i] : ((const float4*)ie)[i - uquads];
        uint2 o;
        o.x = (unsigned)f2bf(v.x) | ((unsigned)f2bf(v.y) << 16);
        o.y = (unsigned)f2bf(v.z) | ((unsigned)f2bf(v.w) << 16);
        ((uint2*)x)[i] = o;
    }
}

// ---------------- W (fp32 [K][N]) -> fragment-ordered bf16 ----------------
// Wf[mat*2048 + (c*4+s)*64 + lane] = 8 bf16: W[s*32+(lane>>4)*8+j][c*16+(lane&15)]
__global__ void k_prepw(const float* __restrict__ Wl1, const float* __restrict__ Wr1,
                        const float* __restrict__ Wl2, const float* __restrict__ Wr2,
                        uint4* __restrict__ Wf) {
    int f = blockIdx.x * 256 + threadIdx.x;
    if (f >= 8192) return;
    int mat = f >> 11, r = f & 2047;
    int lane = r & 63, s = (r >> 6) & 3, c = r >> 8;
    const float* W = (mat == 0) ? Wl1 : (mat == 1) ? Wr1 : (mat == 2) ? Wl2 : Wr2;
    int col = c * 16 + (lane & 15);
    int k0 = s * 32 + (lane >> 4) * 8;
    ushort v[8];
#pragma unroll
    for (int j = 0; j < 8; ++j) v[j] = f2bf(W[(k0 + j) * HID + col]);
    uint4 o;
    o.x = (unsigned)v[0] | ((unsigned)v[1] << 16);
    o.y = (unsigned)v[2] | ((unsigned)v[3] << 16);
    o.z = (unsigned)v[4] | ((unsigned)v[5] << 16);
    o.w = (unsigned)v[6] | ((unsigned)v[7] << 16);
    Wf[f] = o;
}

// ---------------- degree histogram ----------------
__global__ void k_deg(const int* __restrict__ dst, int* __restrict__ deg) {
    for (int i = blockIdx.x * blockDim.x + threadIdx.x; i < N_EDGES; i += gridDim.x * blockDim.x)
        atomicAdd(&deg[dst[i]], 1);
}

// ---------------- hierarchical exclusive scan ----------------
__global__ void k_scan1(const int* __restrict__ deg, int* __restrict__ rowp,
                        int* __restrict__ partials, float* __restrict__ invd) {
    __shared__ int s[256];
    int t = threadIdx.x;
    int i = blockIdx.x * 256 + t;
    int v = (i < N_NODES) ? deg[i] : 0;
    if (i < N_NODES) invd[i] = 1.0f / (float)max(v, 1);
    s[t] = v;
    __syncthreads();
    for (int off = 1; off < 256; off <<= 1) {
        int add = (t >= off) ? s[t - off] : 0;
        __syncthreads();
        s[t] += add;
        __syncthreads();
    }
    if (i < N_NODES) rowp[i] = s[t] - v;
    if (t == 255) partials[blockIdx.x] = s[255];
}

__global__ void k_scan2(const int* __restrict__ partials, int* __restrict__ poff, int nparts) {
    __shared__ int s[512];
    int t = threadIdx.x;
    int v = (t < nparts) ? partials[t] : 0;
    s[t] = v;
    __syncthreads();
    for (int off = 1; off < 512; off <<= 1) {
        int add = (t >= off) ? s[t - off] : 0;
        __syncthreads();
        s[t] += add;
        __syncthreads();
    }
    poff[t] = s[t] - v;
}

__global__ void k_scan3(int* __restrict__ rowp, const int* __restrict__ poff,
                        int* __restrict__ wptr) {
    int i = blockIdx.x * 256 + threadIdx.x;
    if (i < N_NODES) {
        int r = rowp[i] + poff[blockIdx.x];
        rowp[i] = r;
        wptr[i] = r;
    }
    if (i == 0) rowp[N_NODES] = N_EDGES;
}

// ---------------- CSR fill ----------------
__global__ void k_fill(const int* __restrict__ src, const int* __restrict__ dst,
                       int* __restrict__ wptr, int* __restrict__ csr) {
    for (int i = blockIdx.x * blockDim.x + threadIdx.x; i < N_EDGES; i += gridDim.x * blockDim.x) {
        int d = dst[i];
        int pos = atomicAdd(&wptr[d], 1);
        csr[pos] = src[i];
    }
}

// ---------------- mean aggregation (bf16 in/out, fp32 accum) ----------------
// one wave per node; lane handles elements 2*lane, 2*lane+1
__global__ void k_agg(const ushort* __restrict__ x, const int* __restrict__ rowp,
                      const int* __restrict__ csr, const float* __restrict__ invd,
                      ushort* __restrict__ agg) {
    int wave = threadIdx.x >> 6, lane = threadIdx.x & 63;
    int n = blockIdx.x * 4 + wave;
    if (n >= N_NODES) return;
    int e0 = rowp[n], e1 = rowp[n + 1];
    const unsigned* xp = (const unsigned*)x;
    float a0 = 0.f, a1 = 0.f;
    int e = e0;
    for (; e + 1 < e1; e += 2) {
        int s0 = csr[e], s1 = csr[e + 1];
        unsigned u = xp[s0 * 64 + lane];
        unsigned v = xp[s1 * 64 + lane];
        a0 += bflo(u) + bflo(v);
        a1 += bfhi(u) + bfhi(v);
    }
    if (e < e1) {
        unsigned u = xp[csr[e] * 64 + lane];
        a0 += bflo(u);
        a1 += bfhi(u);
    }
    float w = invd[n];
    ((unsigned*)agg)[n * 64 + lane] = (unsigned)f2bf(a0 * w) | ((unsigned)f2bf(a1 * w) << 16);
}

// ---------------- MFMA GEMM: out = A1@W1 + A2@W2 + bias (bf16) ----------------
// block = 256 thr = 4 waves; 128 rows/block; wave handles 32 rows x 128 cols.
// W fragments (both matrices, 64 KB) staged in LDS; A fragments direct global.
// out may alias A1/A2 (each block/wave reads only the rows it later writes).
__global__ __launch_bounds__(256) void k_gemm(const ushort* __restrict__ A1,
                                              const ushort* __restrict__ A2,
                                              const uint4* __restrict__ Wf1,
                                              const uint4* __restrict__ Wf2,
                                              const float* __restrict__ bias,
                                              ushort* __restrict__ out) {
    __shared__ uint4 sW[4096];  // [mat][ (c*4+s)*64 + lane ] -> 64 KB
    int t = threadIdx.x;
#pragma unroll
    for (int i = 0; i < 8; ++i) sW[t + i * 256] = Wf1[t + i * 256];
#pragma unroll
    for (int i = 0; i < 8; ++i) sW[2048 + t + i * 256] = Wf2[t + i * 256];
    __syncthreads();

    int w = t >> 6, lane = t & 63;
    int r0 = blockIdx.x * 128 + w * 32;
    int rowA = lane & 15, hi = lane >> 4;  // A-frag: row=lane&15, k=hi*8+j

    const ushort* Arow1 = A1 + (size_t)(r0 + rowA) * HID;
    const ushort* Arow2 = A2 + (size_t)(r0 + rowA) * HID;

    f32x4 acc[2][8];
#pragma unroll
    for (int rt = 0; rt < 2; ++rt)
#pragma unroll
        for (int c = 0; c < 8; ++c) acc[rt][c] = (f32x4){0.f, 0.f, 0.f, 0.f};

#pragma unroll
    for (int mat = 0; mat < 2; ++mat) {
        const ushort* Ab = mat ? Arow2 : Arow1;
        const uint4* sWm = &sW[mat * 2048];
#pragma unroll
        for (int s = 0; s < 4; ++s) {
            bf16x8 a0 = *(const bf16x8*)(Ab + s * 32 + hi * 8);
            bf16x8 a1 = *(const bf16x8*)(Ab + 16 * HID + s * 32 + hi * 8);
#pragma unroll
            for (int c = 0; c < 8; ++c) {
                bf16x8 b = *(const bf16x8*)&sWm[(c * 4 + s) * 64 + lane];
                acc[0][c] = __builtin_amdgcn_mfma_f32_16x16x32_bf16(a0, b, acc[0][c], 0, 0, 0);
                acc[1][c] = __builtin_amdgcn_mfma_f32_16x16x32_bf16(a1, b, acc[1][c], 0, 0, 0);
            }
        }
    }

    // C layout: col = lane&15, row(in tile) = hi*4 + reg
#pragma unroll
    for (int c = 0; c < 8; ++c) {
        int col = c * 16 + (lane & 15);
        float bv = bias[col];
#pragma unroll
        for (int rt = 0; rt < 2; ++rt) {
#pragma unroll
            for (int reg = 0; reg < 4; ++reg) {
                int row = r0 + rt * 16 + hi * 4 + reg;
                out[(size_t)row * HID + col] = f2bf(acc[rt][c][reg] + bv);
            }
        }
    }
}

// ---------------- y[n] = x[n] . W_out + b_out (x bf16) ----------------
__global__ void k_ydot(const ushort* __restrict__ x, const float* __restrict__ Wout,
                       const float* __restrict__ bout, float* __restrict__ y) {
    int wave = threadIdx.x >> 6, lane = threadIdx.x & 63;
    int n = blockIdx.x * 4 + wave;
    if (n >= N_NODES) return;
    unsigned u = ((const unsigned*)x)[n * 64 + lane];
    float d = bflo(u) * Wout[2 * lane] + bfhi(u) * Wout[2 * lane + 1];
#pragma unroll
    for (int off = 32; off; off >>= 1) d += __shfl_down(d, off, 64);
    if (lane == 0) y[n] = d + bout[0];
}

// ---------------- softmax over gathered items ----------------
__device__ inline unsigned fkey(float x) {
    unsigned u = __float_as_uint(x);
    return (u & 0x80000000u) ? ~u : (u | 0x80000000u);
}
__device__ inline float funkey(unsigned k) {
    unsigned u = (k & 0x80000000u) ? (k & 0x7fffffffu) : ~k;
    return __uint_as_float(u);
}

__global__ void k_max(const float* __restrict__ y, const int* __restrict__ item,
                      unsigned* __restrict__ redmax) {
    float m = -3.4e38f;
    for (int i = blockIdx.x * blockDim.x + threadIdx.x; i < N_ITEMS; i += gridDim.x * blockDim.x)
        m = fmaxf(m, y[item[i]]);
#pragma unroll
    for (int off = 32; off; off >>= 1) m = fmaxf(m, __shfl_down(m, off, 64));
    __shared__ float sm[4];
    int lane = threadIdx.x & 63, wave = threadIdx.x >> 6;
    if (lane == 0) sm[wave] = m;
    __syncthreads();
    if (threadIdx.x == 0) {
        float mm = fmaxf(fmaxf(sm[0], sm[1]), fmaxf(sm[2], sm[3]));
        atomicMax(redmax, fkey(mm));
    }
}

__global__ void k_sumexp(const float* __restrict__ y, const int* __restrict__ item,
                         const unsigned* __restrict__ redmax, float* __restrict__ redsum) {
    float m = funkey(*redmax);
    float s = 0.f;
    for (int i = blockIdx.x * blockDim.x + threadIdx.x; i < N_ITEMS; i += gridDim.x * blockDim.x)
        s += expf(y[item[i]] - m);
#pragma unroll
    for (int off = 32; off; off >>= 1) s += __shfl_down(s, off, 64);
    __shared__ float sm[4];
    int lane = threadIdx.x & 63, wave = threadIdx.x >> 6;
    if (lane == 0) sm[wave] = s;
    __syncthreads();
    if (threadIdx.x == 0) atomicAdd(redsum, sm[0] + sm[1] + sm[2] + sm[3]);
}

__global__ void k_out(const float* __restrict__ y, const int* __restrict__ item,
                      const unsigned* __restrict__ redmax, const float* __restrict__ redsum,
                      const float* __restrict__ dprior, float* __restrict__ out) {
    float m = funkey(*redmax);
    float inv_s = 1.0f / (*redsum);
    float pr = fmaxf(dprior[0], 0.f);
    for (int i = blockIdx.x * blockDim.x + threadIdx.x; i < N_ITEMS; i += gridDim.x * blockDim.x)
        out[i] = pr * expf(y[item[i]] - m) * inv_s;
}

extern "C" void kernel_launch(void* const* d_in, const int* in_sizes, int n_in,
                              void* d_out, int out_size, void* d_ws, size_t ws_size,
                              hipStream_t stream) {
    const int*   item  = (const int*)d_in[0];
    const int*   esrc  = (const int*)d_in[1];
    const int*   edst  = esrc + N_EDGES;
    const float* ue    = (const float*)d_in[2];
    const float* ie    = (const float*)d_in[3];
    const float* Wl1   = (const float*)d_in[4];
    const float* Wr1   = (const float*)d_in[5];
    const float* b1    = (const float*)d_in[6];
    const float* Wl2   = (const float*)d_in[7];
    const float* Wr2   = (const float*)d_in[8];
    const float* b2    = (const float*)d_in[9];
    const float* Wout  = (const float*)d_in[10];
    const float* bout  = (const float*)d_in[11];
    const float* dpri  = (const float*)d_in[12];
    float* out = (float*)d_out;

    // workspace layout (~60 MB)
    ushort* xA  = (ushort*)d_ws;                      // MPAD*128 bf16
    ushort* xB  = xA + (size_t)MPAD * HID;            // MPAD*128 bf16
    uint4*  Wf  = (uint4*)(xB + (size_t)MPAD * HID);  // 8192 uint4 (4 mats)
    int*    deg = (int*)(Wf + 8192);                  // 100096
    float*  invd = (float*)(deg + MPAD);              // 100096
    int*    rowp = (int*)(invd + MPAD);               // 100100
    int*    wptr = rowp + 100100;                     // 100100
    int*    parts = wptr + 100100;                    // 512
    int*    poff  = parts + 512;                      // 512
    int*    csr   = poff + 512;                       // 1.6M
    float*  y     = (float*)(csr + N_EDGES);          // 100000
    unsigned* redmax = (unsigned*)(y + N_NODES);
    float*  redsum = (float*)(redmax + 1);

    const int SCAN_BLOCKS = (N_NODES + 255) / 256;  // 391

    hipMemsetAsync(deg, 0, N_NODES * sizeof(int), stream);
    hipMemsetAsync((void*)redmax, 0, 8, stream);  // redmax=0(key(-inf) floor), redsum=0.f

    k_build_x<<<2048, 256, 0, stream>>>(ue, ie, xA);
    k_prepw<<<32, 256, 0, stream>>>(Wl1, Wr1, Wl2, Wr2, Wf);
    k_deg<<<2048, 256, 0, stream>>>(edst, deg);
    k_scan1<<<SCAN_BLOCKS, 256, 0, stream>>>(deg, rowp, parts, invd);
    k_scan2<<<1, 512, 0, stream>>>(parts, poff, SCAN_BLOCKS);
    k_scan3<<<SCAN_BLOCKS, 256, 0, stream>>>(rowp, poff, wptr);
    k_fill<<<2048, 256, 0, stream>>>(esrc, edst, wptr, csr);

    // layer 1: x = xA ; agg -> xB ; gemm(agg=xB, x=xA) -> xB
    k_agg<<<N_NODES / 4, 256, 0, stream>>>(xA, rowp, csr, invd, xB);
    k_gemm<<<MPAD / 128, 256, 0, stream>>>(xB, xA, Wf, Wf + 2048, b1, xB);
    // layer 2: x = xB ; agg -> xA ; gemm -> xA
    k_agg<<<N_NODES / 4, 256, 0, stream>>>(xB, rowp, csr, invd, xA);
    k_gemm<<<MPAD / 128, 256, 0, stream>>>(xA, xB, Wf + 4096, Wf + 6144, b2, xA);

    k_ydot<<<N_NODES / 4, 256, 0, stream>>>(xA, Wout, bout, y);
    k_max<<<200, 256, 0, stream>>>(y, item, redmax);
    k_sumexp<<<200, 256, 0, stream>>>(y, item, redmax, redsum);
    k_out<<<200, 256, 0, stream>>>(y, item, redmax, redsum, dpri, out);
}

// Round 3
// 490.375 us; speedup vs baseline: 1.7190x; 1.1705x over previous
//
#include <hip/hip_runtime.h>
#include <math.h>

#define N_USERS 50000
#define N_ITEMS 50000
#define N_NODES 100000
#define MPAD    100096   // padded rows: 782 blocks * 128
#define HID     128
#define N_EDGES 1600000

// CSR-build partition parameters
#define BKTW 512                  // nodes per dst-bucket
#define NBKT 196                  // ceil(N_NODES / BKTW)
#define NCOL 256                  // pass-A blocks
#define EPB  (N_EDGES / NCOL)     // 6250 edges per pass-A block
#define NH   (NBKT * NCOL)        // 50176 (bucket, block) counts

typedef __attribute__((ext_vector_type(8))) short bf16x8;
typedef __attribute__((ext_vector_type(4))) float f32x4;

static __device__ inline ushort f2bf(float f) {
    unsigned u = __float_as_uint(f);
    unsigned r = (u + 0x7fffu + ((u >> 16) & 1u)) >> 16;  // RNE
    return (ushort)r;
}
static __device__ inline float bflo(unsigned v) { return __uint_as_float(v << 16); }
static __device__ inline float bfhi(unsigned v) { return __uint_as_float(v & 0xffff0000u); }

// ---------------- x = concat(user_emb, item_emb) -> bf16 ----------------
__global__ void k_build_x(const float* __restrict__ ue, const float* __restrict__ ie,
                          ushort* __restrict__ x) {
    const int total = N_NODES * HID / 4;
    const int uquads = N_USERS * HID / 4;
    for (int i = blockIdx.x * blockDim.x + threadIdx.x; i < total; i += gridDim.x * blockDim.x) {
        float4 v = (i < uquads) ? ((const float4*)ue)[i] : ((const float4*)ie)[i - uquads];
        uint2 o;
        o.x = (unsigned)f2bf(v.x) | ((unsigned)f2bf(v.y) << 16);
        o.y = (unsigned)f2bf(v.z) | ((unsigned)f2bf(v.w) << 16);
        ((uint2*)x)[i] = o;
    }
}

// ---------------- W (fp32 [K][N]) -> fragment-ordered bf16 ----------------
__global__ void k_prepw(const float* __restrict__ Wl1, const float* __restrict__ Wr1,
                        const float* __restrict__ Wl2, const float* __restrict__ Wr2,
                        uint4* __restrict__ Wf) {
    int f = blockIdx.x * 256 + threadIdx.x;
    if (f >= 8192) return;
    int mat = f >> 11, r = f & 2047;
    int lane = r & 63, s = (r >> 6) & 3, c = r >> 8;
    const float* W = (mat == 0) ? Wl1 : (mat == 1) ? Wr1 : (mat == 2) ? Wl2 : Wr2;
    int col = c * 16 + (lane & 15);
    int k0 = s * 32 + (lane >> 4) * 8;
    ushort v[8];
#pragma unroll
    for (int j = 0; j < 8; ++j) v[j] = f2bf(W[(k0 + j) * HID + col]);
    uint4 o;
    o.x = (unsigned)v[0] | ((unsigned)v[1] << 16);
    o.y = (unsigned)v[2] | ((unsigned)v[3] << 16);
    o.z = (unsigned)v[4] | ((unsigned)v[5] << 16);
    o.w = (unsigned)v[6] | ((unsigned)v[7] << 16);
    Wf[f] = o;
}

// ---------------- pass A1: per-block bucket histogram + node degrees ----------------
__global__ __launch_bounds__(512) void k_histdeg(const int* __restrict__ dst,
                                                 int* __restrict__ deg,
                                                 int* __restrict__ histc) {
    __shared__ int lh[NBKT];
    int t = threadIdx.x, k = blockIdx.x;
    for (int i = t; i < NBKT; i += 512) lh[i] = 0;
    __syncthreads();
    int e0 = k * EPB, e1 = e0 + EPB;
    for (int e = e0 + t; e < e1; e += 512) {
        int d = dst[e];
        atomicAdd(&lh[d >> 9], 1);
        atomicAdd(&deg[d], 1);
    }
    __syncthreads();
    for (int i = t; i < NBKT; i += 512) histc[i * NCOL + k] = lh[i];
}

// ---------------- generic hierarchical exclusive scan ----------------
__global__ void k_gscan1(const int* __restrict__ in, int* __restrict__ out,
                         int* __restrict__ partials, int n) {
    __shared__ int s[256];
    int t = threadIdx.x;
    int i = blockIdx.x * 256 + t;
    int v = (i < n) ? in[i] : 0;
    s[t] = v;
    __syncthreads();
    for (int off = 1; off < 256; off <<= 1) {
        int add = (t >= off) ? s[t - off] : 0;
        __syncthreads();
        s[t] += add;
        __syncthreads();
    }
    if (i < n) out[i] = s[t] - v;
    if (t == 255) partials[blockIdx.x] = s[255];
}

__global__ void k_scan2(const int* __restrict__ partials, int* __restrict__ poff, int nparts) {
    __shared__ int s[512];
    int t = threadIdx.x;
    int v = (t < nparts) ? partials[t] : 0;
    s[t] = v;
    __syncthreads();
    for (int off = 1; off < 512; off <<= 1) {
        int add = (t >= off) ? s[t - off] : 0;
        __syncthreads();
        s[t] += add;
        __syncthreads();
    }
    poff[t] = s[t] - v;
}

__global__ void k_gscan3(int* __restrict__ out, const int* __restrict__ poff, int n) {
    int i = blockIdx.x * 256 + threadIdx.x;
    if (i < n) out[i] += poff[blockIdx.x];
}

// ---------------- node scan (rowp) + invd ----------------
__global__ void k_scan1(const int* __restrict__ deg, int* __restrict__ rowp,
                        int* __restrict__ partials, float* __restrict__ invd) {
    __shared__ int s[256];
    int t = threadIdx.x;
    int i = blockIdx.x * 256 + t;
    int v = (i < N_NODES) ? deg[i] : 0;
    if (i < N_NODES) invd[i] = 1.0f / (float)max(v, 1);
    s[t] = v;
    __syncthreads();
    for (int off = 1; off < 256; off <<= 1) {
        int add = (t >= off) ? s[t - off] : 0;
        __syncthreads();
        s[t] += add;
        __syncthreads();
    }
    if (i < N_NODES) rowp[i] = s[t] - v;
    if (t == 255) partials[blockIdx.x] = s[255];
}

__global__ void k_scan3n(int* __restrict__ rowp, const int* __restrict__ poff) {
    int i = blockIdx.x * 256 + threadIdx.x;
    if (i < N_NODES) rowp[i] += poff[blockIdx.x];
    if (i == 0) rowp[N_NODES] = N_EDGES;
}

// ---------------- pass A2: scatter (src,dst) into bucket-partitioned array ----------------
__global__ __launch_bounds__(512) void k_scatA(const int* __restrict__ src,
                                               const int* __restrict__ dst,
                                               const int* __restrict__ hists,
                                               uint2* __restrict__ part) {
    __shared__ int cur[NBKT];
    int t = threadIdx.x, k = blockIdx.x;
    for (int i = t; i < NBKT; i += 512) cur[i] = hists[i * NCOL + k];
    __syncthreads();
    int e0 = k * EPB, e1 = e0 + EPB;
    for (int e = e0 + t; e < e1; e += 512) {
        int s = src[e], d = dst[e];
        int pos = atomicAdd(&cur[d >> 9], 1);
        part[pos] = make_uint2((unsigned)s, (unsigned)d);
    }
}

// ---------------- pass B: per-bucket fine scatter into csr ----------------
__global__ __launch_bounds__(512) void k_scatB(const uint2* __restrict__ part,
                                               const int* __restrict__ hists,
                                               const int* __restrict__ rowp,
                                               int* __restrict__ csr) {
    __shared__ int lptr[BKTW];
    int t = threadIdx.x, b = blockIdx.x;
    int nb = b * BKTW;
    for (int i = t; i < BKTW; i += 512) {
        int n = nb + i;
        lptr[i] = (n < N_NODES) ? rowp[n] : N_EDGES;
    }
    __syncthreads();
    int p0 = hists[b * NCOL];
    int p1 = (b + 1 < NBKT) ? hists[(b + 1) * NCOL] : N_EDGES;
    for (int e = p0 + t; e < p1; e += 512) {
        uint2 ed = part[e];
        int pos = atomicAdd(&lptr[ed.y - (unsigned)nb], 1);
        csr[pos] = (int)ed.x;
    }
}

// ---------------- mean aggregation (bf16 in/out, fp32 accum) ----------------
__global__ void k_agg(const ushort* __restrict__ x, const int* __restrict__ rowp,
                      const int* __restrict__ csr, const float* __restrict__ invd,
                      ushort* __restrict__ agg) {
    int wave = threadIdx.x >> 6, lane = threadIdx.x & 63;
    int n = blockIdx.x * 4 + wave;
    if (n >= N_NODES) return;
    int e0 = rowp[n], e1 = rowp[n + 1];
    const unsigned* xp = (const unsigned*)x;
    float a0 = 0.f, a1 = 0.f;
    int e = e0;
    for (; e + 1 < e1; e += 2) {
        int s0 = csr[e], s1 = csr[e + 1];
        unsigned u = xp[s0 * 64 + lane];
        unsigned v = xp[s1 * 64 + lane];
        a0 += bflo(u) + bflo(v);
        a1 += bfhi(u) + bfhi(v);
    }
    if (e < e1) {
        unsigned u = xp[csr[e] * 64 + lane];
        a0 += bflo(u);
        a1 += bfhi(u);
    }
    float w = invd[n];
    ((unsigned*)agg)[n * 64 + lane] = (unsigned)f2bf(a0 * w) | ((unsigned)f2bf(a1 * w) << 16);
}

// ---------------- MFMA GEMM: out = A1@W1 + A2@W2 + bias (bf16) ----------------
__global__ __launch_bounds__(256) void k_gemm(const ushort* __restrict__ A1,
                                              const ushort* __restrict__ A2,
                                              const uint4* __restrict__ Wf1,
                                              const uint4* __restrict__ Wf2,
                                              const float* __restrict__ bias,
                                              ushort* __restrict__ out) {
    __shared__ uint4 sW[4096];  // 64 KB
    int t = threadIdx.x;
#pragma unroll
    for (int i = 0; i < 8; ++i) sW[t + i * 256] = Wf1[t + i * 256];
#pragma unroll
    for (int i = 0; i < 8; ++i) sW[2048 + t + i * 256] = Wf2[t + i * 256];
    __syncthreads();

    int w = t >> 6, lane = t & 63;
    int r0 = blockIdx.x * 128 + w * 32;
    int rowA = lane & 15, hi = lane >> 4;

    const ushort* Arow1 = A1 + (size_t)(r0 + rowA) * HID;
    const ushort* Arow2 = A2 + (size_t)(r0 + rowA) * HID;

    f32x4 acc[2][8];
#pragma unroll
    for (int rt = 0; rt < 2; ++rt)
#pragma unroll
        for (int c = 0; c < 8; ++c) acc[rt][c] = (f32x4){0.f, 0.f, 0.f, 0.f};

#pragma unroll
    for (int mat = 0; mat < 2; ++mat) {
        const ushort* Ab = mat ? Arow2 : Arow1;
        const uint4* sWm = &sW[mat * 2048];
#pragma unroll
        for (int s = 0; s < 4; ++s) {
            bf16x8 a0 = *(const bf16x8*)(Ab + s * 32 + hi * 8);
            bf16x8 a1 = *(const bf16x8*)(Ab + 16 * HID + s * 32 + hi * 8);
#pragma unroll
            for (int c = 0; c < 8; ++c) {
                bf16x8 b = *(const bf16x8*)&sWm[(c * 4 + s) * 64 + lane];
                acc[0][c] = __builtin_amdgcn_mfma_f32_16x16x32_bf16(a0, b, acc[0][c], 0, 0, 0);
                acc[1][c] = __builtin_amdgcn_mfma_f32_16x16x32_bf16(a1, b, acc[1][c], 0, 0, 0);
            }
        }
    }

#pragma unroll
    for (int c = 0; c < 8; ++c) {
        int col = c * 16 + (lane & 15);
        float bv = bias[col];
#pragma unroll
        for (int rt = 0; rt < 2; ++rt) {
#pragma unroll
            for (int reg = 0; reg < 4; ++reg) {
                int row = r0 + rt * 16 + hi * 4 + reg;
                out[(size_t)row * HID + col] = f2bf(acc[rt][c][reg] + bv);
            }
        }
    }
}

// ---------------- y[n] = x[n] . W_out + b_out (x bf16) ----------------
__global__ void k_ydot(const ushort* __restrict__ x, const float* __restrict__ Wout,
                       const float* __restrict__ bout, float* __restrict__ y) {
    int wave = threadIdx.x >> 6, lane = threadIdx.x & 63;
    int n = blockIdx.x * 4 + wave;
    if (n >= N_NODES) return;
    unsigned u = ((const unsigned*)x)[n * 64 + lane];
    float d = bflo(u) * Wout[2 * lane] + bfhi(u) * Wout[2 * lane + 1];
#pragma unroll
    for (int off = 32; off; off >>= 1) d += __shfl_down(d, off, 64);
    if (lane == 0) y[n] = d + bout[0];
}

// ---------------- softmax over gathered items ----------------
__device__ inline unsigned fkey(float x) {
    unsigned u = __float_as_uint(x);
    return (u & 0x80000000u) ? ~u : (u | 0x80000000u);
}
__device__ inline float funkey(unsigned k) {
    unsigned u = (k & 0x80000000u) ? (k & 0x7fffffffu) : ~k;
    return __uint_as_float(u);
}

__global__ void k_max(const float* __restrict__ y, const int* __restrict__ item,
                      unsigned* __restrict__ redmax) {
    float m = -3.4e38f;
    for (int i = blockIdx.x * blockDim.x + threadIdx.x; i < N_ITEMS; i += gridDim.x * blockDim.x)
        m = fmaxf(m, y[item[i]]);
#pragma unroll
    for (int off = 32; off; off >>= 1) m = fmaxf(m, __shfl_down(m, off, 64));
    __shared__ float sm[4];
    int lane = threadIdx.x & 63, wave = threadIdx.x >> 6;
    if (lane == 0) sm[wave] = m;
    __syncthreads();
    if (threadIdx.x == 0) {
        float mm = fmaxf(fmaxf(sm[0], sm[1]), fmaxf(sm[2], sm[3]));
        atomicMax(redmax, fkey(mm));
    }
}

__global__ void k_sumexp(const float* __restrict__ y, const int* __restrict__ item,
                         const unsigned* __restrict__ redmax, float* __restrict__ redsum) {
    float m = funkey(*redmax);
    float s = 0.f;
    for (int i = blockIdx.x * blockDim.x + threadIdx.x; i < N_ITEMS; i += gridDim.x * blockDim.x)
        s += expf(y[item[i]] - m);
#pragma unroll
    for (int off = 32; off; off >>= 1) s += __shfl_down(s, off, 64);
    __shared__ float sm[4];
    int lane = threadIdx.x & 63, wave = threadIdx.x >> 6;
    if (lane == 0) sm[wave] = s;
    __syncthreads();
    if (threadIdx.x == 0) atomicAdd(redsum, sm[0] + sm[1] + sm[2] + sm[3]);
}

__global__ void k_out(const float* __restrict__ y, const int* __restrict__ item,
                      const unsigned* __restrict__ redmax, const float* __restrict__ redsum,
                      const float* __restrict__ dprior, float* __restrict__ out) {
    float m = funkey(*redmax);
    float inv_s = 1.0f / (*redsum);
    float pr = fmaxf(dprior[0], 0.f);
    for (int i = blockIdx.x * blockDim.x + threadIdx.x; i < N_ITEMS; i += gridDim.x * blockDim.x)
        out[i] = pr * expf(y[item[i]] - m) * inv_s;
}

extern "C" void kernel_launch(void* const* d_in, const int* in_sizes, int n_in,
                              void* d_out, int out_size, void* d_ws, size_t ws_size,
                              hipStream_t stream) {
    const int*   item  = (const int*)d_in[0];
    const int*   esrc  = (const int*)d_in[1];
    const int*   edst  = esrc + N_EDGES;
    const float* ue    = (const float*)d_in[2];
    const float* ie    = (const float*)d_in[3];
    const float* Wl1   = (const float*)d_in[4];
    const float* Wr1   = (const float*)d_in[5];
    const float* b1    = (const float*)d_in[6];
    const float* Wl2   = (const float*)d_in[7];
    const float* Wr2   = (const float*)d_in[8];
    const float* b2    = (const float*)d_in[9];
    const float* Wout  = (const float*)d_in[10];
    const float* bout  = (const float*)d_in[11];
    const float* dpri  = (const float*)d_in[12];
    float* out = (float*)d_out;

    // workspace layout (~73 MB): big aligned arrays first
    ushort* xA   = (ushort*)d_ws;                      // MPAD*128 bf16
    ushort* xB   = xA + (size_t)MPAD * HID;            // MPAD*128 bf16
    uint4*  Wf   = (uint4*)(xB + (size_t)MPAD * HID);  // 8192 uint4
    uint2*  part = (uint2*)(Wf + 8192);                // N_EDGES uint2 (12.8 MB)
    int*    csr  = (int*)(part + N_EDGES);             // N_EDGES
    int*    deg  = csr + N_EDGES;                      // MPAD
    float*  invd = (float*)(deg + MPAD);               // MPAD
    int*    rowp = (int*)(invd + MPAD);                // 100104
    int*    parts_n = rowp + 100104;                   // 512
    int*    poff_n  = parts_n + 512;                   // 512
    int*    histc   = poff_n + 512;                    // NH = 50176
    int*    hists   = histc + NH;                      // NH
    int*    parts_h = hists + NH;                      // 512
    int*    poff_h  = parts_h + 512;                   // 512
    float*  y       = (float*)(poff_h + 512);          // N_NODES
    unsigned* redmax = (unsigned*)(y + N_NODES);
    float*  redsum = (float*)(redmax + 1);

    const int SCAN_N = (N_NODES + 255) / 256;  // 391
    const int SCAN_H = NH / 256;               // 196

    hipMemsetAsync(deg, 0, N_NODES * sizeof(int), stream);
    hipMemsetAsync((void*)redmax, 0, 8, stream);

    k_build_x<<<2048, 256, 0, stream>>>(ue, ie, xA);
    k_prepw<<<32, 256, 0, stream>>>(Wl1, Wr1, Wl2, Wr2, Wf);

    // CSR build: histogram + degrees, scans, two-pass partition scatter
    k_histdeg<<<NCOL, 512, 0, stream>>>(edst, deg, histc);
    k_scan1<<<SCAN_N, 256, 0, stream>>>(deg, rowp, parts_n, invd);
    k_scan2<<<1, 512, 0, stream>>>(parts_n, poff_n, SCAN_N);
    k_scan3n<<<SCAN_N, 256, 0, stream>>>(rowp, poff_n);
    k_gscan1<<<SCAN_H, 256, 0, stream>>>(histc, hists, parts_h, NH);
    k_scan2<<<1, 512, 0, stream>>>(parts_h, poff_h, SCAN_H);
    k_gscan3<<<SCAN_H, 256, 0, stream>>>(hists, poff_h, NH);
    k_scatA<<<NCOL, 512, 0, stream>>>(esrc, edst, hists, part);
    k_scatB<<<NBKT, 512, 0, stream>>>(part, hists, rowp, csr);

    // layer 1: x = xA ; agg -> xB ; gemm(agg=xB, x=xA) -> xB
    k_agg<<<N_NODES / 4, 256, 0, stream>>>(xA, rowp, csr, invd, xB);
    k_gemm<<<MPAD / 128, 256, 0, stream>>>(xB, xA, Wf, Wf + 2048, b1, xB);
    // layer 2: x = xB ; agg -> xA ; gemm -> xA
    k_agg<<<N_NODES / 4, 256, 0, stream>>>(xB, rowp, csr, invd, xA);
    k_gemm<<<MPAD / 128, 256, 0, stream>>>(xA, xB, Wf + 4096, Wf + 6144, b2, xA);

    k_ydot<<<N_NODES / 4, 256, 0, stream>>>(xA, Wout, bout, y);
    k_max<<<200, 256, 0, stream>>>(y, item, redmax);
    k_sumexp<<<200, 256, 0, stream>>>(y, item, redmax, redsum);
    k_out<<<200, 256, 0, stream>>>(y, item, redmax, redsum, dpri, out);
}

// Round 4
// 381.062 us; speedup vs baseline: 2.2122x; 1.2869x over previous
//
#include <hip/hip_runtime.h>
#include <math.h>

#define N_USERS 50000
#define N_ITEMS 50000
#define N_NODES 100000
#define MPAD    100096   // padded rows: 782 blocks * 128
#define HID     128
#define N_EDGES 1600000

// CSR-build partition parameters
#define BKTW 512                  // nodes per dst-bucket
#define NBKT 196                  // ceil(N_NODES / BKTW)
#define NCOL 256                  // pass-A blocks
#define EPB  (N_EDGES / NCOL)     // 6250 edges per pass-A block
#define NH   (NBKT * NCOL)        // 50176 (bucket, block) counts
#define SCAN_N 391                // ceil(N_NODES/256)
#define SCAN_H 196                // NH/256

#define FP8_SCALE     64.0f
#define FP8_INV_SCALE 0.015625f

typedef __attribute__((ext_vector_type(8))) short bf16x8;
typedef __attribute__((ext_vector_type(4))) float f32x4;
typedef __attribute__((ext_vector_type(2))) float f32x2;

static __device__ inline ushort f2bf(float f) {
    unsigned u = __float_as_uint(f);
    unsigned r = (u + 0x7fffu + ((u >> 16) & 1u)) >> 16;  // RNE
    return (ushort)r;
}
static __device__ inline float bflo(unsigned v) { return __uint_as_float(v << 16); }
static __device__ inline float bfhi(unsigned v) { return __uint_as_float(v & 0xffff0000u); }

// pack 4 floats -> 4 fp8 e4m3 bytes (pre-scaled)
static __device__ inline unsigned pk4_fp8(float v0, float v1, float v2, float v3) {
    unsigned w = __builtin_amdgcn_cvt_pk_fp8_f32(v0, v1, 0, false);
    w = __builtin_amdgcn_cvt_pk_fp8_f32(v2, v3, w, true);
    return w;
}

// ---------------- x = concat(user,item)->bf16 + fp8 shadow ; fused k_prepw ----------------
__global__ void k_build_x(const float* __restrict__ ue, const float* __restrict__ ie,
                          ushort* __restrict__ x, unsigned* __restrict__ x8,
                          const float* __restrict__ Wl1, const float* __restrict__ Wr1,
                          const float* __restrict__ Wl2, const float* __restrict__ Wr2,
                          uint4* __restrict__ Wf) {
    if (blockIdx.x >= 2048) {  // fused W-fragment prep
        int f = (blockIdx.x - 2048) * 256 + threadIdx.x;
        if (f >= 8192) return;
        int mat = f >> 11, r = f & 2047;
        int lane = r & 63, s = (r >> 6) & 3, c = r >> 8;
        const float* W = (mat == 0) ? Wl1 : (mat == 1) ? Wr1 : (mat == 2) ? Wl2 : Wr2;
        int col = c * 16 + (lane & 15);
        int k0 = s * 32 + (lane >> 4) * 8;
        ushort v[8];
#pragma unroll
        for (int j = 0; j < 8; ++j) v[j] = f2bf(W[(k0 + j) * HID + col]);
        uint4 o;
        o.x = (unsigned)v[0] | ((unsigned)v[1] << 16);
        o.y = (unsigned)v[2] | ((unsigned)v[3] << 16);
        o.z = (unsigned)v[4] | ((unsigned)v[5] << 16);
        o.w = (unsigned)v[6] | ((unsigned)v[7] << 16);
        Wf[f] = o;
        return;
    }
    const int total = N_NODES * HID / 4;
    const int uquads = N_USERS * HID / 4;
    for (int i = blockIdx.x * blockDim.x + threadIdx.x; i < total; i += 2048 * 256) {
        float4 v = (i < uquads) ? ((const float4*)ue)[i] : ((const float4*)ie)[i - uquads];
        uint2 o;
        o.x = (unsigned)f2bf(v.x) | ((unsigned)f2bf(v.y) << 16);
        o.y = (unsigned)f2bf(v.z) | ((unsigned)f2bf(v.w) << 16);
        ((uint2*)x)[i] = o;
        x8[i] = pk4_fp8(v.x * FP8_SCALE, v.y * FP8_SCALE, v.z * FP8_SCALE, v.w * FP8_SCALE);
    }
}

// ---------------- bf16 rows -> fp8 shadow (for layer-2 gather) ----------------
__global__ void k_enc8(const ushort* __restrict__ x, unsigned* __restrict__ x8) {
    const int total = MPAD * HID / 4;
    for (int i = blockIdx.x * blockDim.x + threadIdx.x; i < total; i += gridDim.x * blockDim.x) {
        uint2 u = ((const uint2*)x)[i];
        x8[i] = pk4_fp8(bflo(u.x) * FP8_SCALE, bfhi(u.x) * FP8_SCALE,
                        bflo(u.y) * FP8_SCALE, bfhi(u.y) * FP8_SCALE);
    }
}

// ---------------- pass A1: per-block bucket histogram + node degrees ----------------
__global__ __launch_bounds__(512) void k_histdeg(const int* __restrict__ dst,
                                                 int* __restrict__ deg,
                                                 int* __restrict__ histc) {
    __shared__ int lh[NBKT];
    int t = threadIdx.x, k = blockIdx.x;
    for (int i = t; i < NBKT; i += 512) lh[i] = 0;
    __syncthreads();
    int e0 = k * EPB, e1 = e0 + EPB;
    for (int e = e0 + t; e < e1; e += 512) {
        int d = dst[e];
        atomicAdd(&lh[d >> 9], 1);
        atomicAdd(&deg[d], 1);
    }
    __syncthreads();
    for (int i = t; i < NBKT; i += 512) histc[i * NCOL + k] = lh[i];
}

// ---------------- scans ----------------
__global__ void k_scan1(const int* __restrict__ deg, int* __restrict__ rowp,
                        int* __restrict__ partials, float* __restrict__ invd) {
    __shared__ int s[256];
    int t = threadIdx.x;
    int i = blockIdx.x * 256 + t;
    int v = (i < N_NODES) ? deg[i] : 0;
    if (i < N_NODES) invd[i] = 1.0f / (float)max(v, 1);
    s[t] = v;
    __syncthreads();
    for (int off = 1; off < 256; off <<= 1) {
        int add = (t >= off) ? s[t - off] : 0;
        __syncthreads();
        s[t] += add;
        __syncthreads();
    }
    if (i < N_NODES) rowp[i] = s[t] - v;
    if (t == 255) partials[blockIdx.x] = s[255];
}

__global__ void k_scan2(const int* __restrict__ partials, int* __restrict__ poff, int nparts) {
    __shared__ int s[512];
    int t = threadIdx.x;
    int v = (t < nparts) ? partials[t] : 0;
    s[t] = v;
    __syncthreads();
    for (int off = 1; off < 512; off <<= 1) {
        int add = (t >= off) ? s[t - off] : 0;
        __syncthreads();
        s[t] += add;
        __syncthreads();
    }
    poff[t] = s[t] - v;
}

// merged: finalize node scan (blocks 0..SCAN_N-1)  ||  hist scan pass1 (blocks SCAN_N..)
__global__ void k_mscan(int* __restrict__ rowp, const int* __restrict__ poff_n,
                        const int* __restrict__ histc, int* __restrict__ hists,
                        int* __restrict__ parts_h) {
    if (blockIdx.x < SCAN_N) {
        int i = blockIdx.x * 256 + threadIdx.x;
        if (i < N_NODES) rowp[i] += poff_n[blockIdx.x];
        if (i == 0) rowp[N_NODES] = N_EDGES;
        return;
    }
    __shared__ int s[256];
    int b = blockIdx.x - SCAN_N;
    int t = threadIdx.x;
    int i = b * 256 + t;
    int v = (i < NH) ? histc[i] : 0;
    s[t] = v;
    __syncthreads();
    for (int off = 1; off < 256; off <<= 1) {
        int add = (t >= off) ? s[t - off] : 0;
        __syncthreads();
        s[t] += add;
        __syncthreads();
    }
    if (i < NH) hists[i] = s[t] - v;
    if (t == 255) parts_h[b] = s[255];
}

__global__ void k_gscan3(int* __restrict__ out, const int* __restrict__ poff, int n) {
    int i = blockIdx.x * 256 + threadIdx.x;
    if (i < n) out[i] += poff[blockIdx.x];
}

// ---------------- pass A2: scatter (src,dst) into bucket-partitioned array ----------------
__global__ __launch_bounds__(512) void k_scatA(const int* __restrict__ src,
                                               const int* __restrict__ dst,
                                               const int* __restrict__ hists,
                                               uint2* __restrict__ part) {
    __shared__ int cur[NBKT];
    int t = threadIdx.x, k = blockIdx.x;
    for (int i = t; i < NBKT; i += 512) cur[i] = hists[i * NCOL + k];
    __syncthreads();
    int e0 = k * EPB, e1 = e0 + EPB;
    for (int e = e0 + t; e < e1; e += 512) {
        int s = src[e], d = dst[e];
        int pos = atomicAdd(&cur[d >> 9], 1);
        part[pos] = make_uint2((unsigned)s, (unsigned)d);
    }
}

// ---------------- pass B: per-bucket fine scatter into csr ----------------
__global__ __launch_bounds__(512) void k_scatB(const uint2* __restrict__ part,
                                               const int* __restrict__ hists,
                                               const int* __restrict__ rowp,
                                               int* __restrict__ csr) {
    __shared__ int lptr[BKTW];
    int t = threadIdx.x, b = blockIdx.x;
    int nb = b * BKTW;
    for (int i = t; i < BKTW; i += 512) {
        int n = nb + i;
        lptr[i] = (n < N_NODES) ? rowp[n] : N_EDGES;
    }
    __syncthreads();
    int p0 = hists[b * NCOL];
    int p1 = (b + 1 < NBKT) ? hists[(b + 1) * NCOL] : N_EDGES;
    for (int e = p0 + t; e < p1; e += 512) {
        uint2 ed = part[e];
        int pos = atomicAdd(&lptr[ed.y - (unsigned)nb], 1);
        csr[pos] = (int)ed.x;
    }
}

// ---------------- mean aggregation: fp8 gather, half-wave per node ----------------
__global__ __launch_bounds__(256) void k_agg(const unsigned* __restrict__ x8,
                                             const int* __restrict__ rowp,
                                             const int* __restrict__ csr,
                                             const float* __restrict__ invd,
                                             ushort* __restrict__ agg) {
    int half = threadIdx.x >> 5, lane = threadIdx.x & 31;
    int n = blockIdx.x * 8 + half;
    int e0 = rowp[n], e1 = rowp[n + 1];
    float a0 = 0.f, a1 = 0.f, a2 = 0.f, a3 = 0.f;
    int e = e0;
    for (; e + 3 < e1; e += 4) {
        int s0 = csr[e], s1 = csr[e + 1], s2 = csr[e + 2], s3 = csr[e + 3];
        unsigned u0 = x8[s0 * 32 + lane];
        unsigned u1 = x8[s1 * 32 + lane];
        unsigned u2 = x8[s2 * 32 + lane];
        unsigned u3 = x8[s3 * 32 + lane];
        f32x2 p;
        p = __builtin_amdgcn_cvt_pk_f32_fp8(u0, false); a0 += p.x; a1 += p.y;
        p = __builtin_amdgcn_cvt_pk_f32_fp8(u0, true);  a2 += p.x; a3 += p.y;
        p = __builtin_amdgcn_cvt_pk_f32_fp8(u1, false); a0 += p.x; a1 += p.y;
        p = __builtin_amdgcn_cvt_pk_f32_fp8(u1, true);  a2 += p.x; a3 += p.y;
        p = __builtin_amdgcn_cvt_pk_f32_fp8(u2, false); a0 += p.x; a1 += p.y;
        p = __builtin_amdgcn_cvt_pk_f32_fp8(u2, true);  a2 += p.x; a3 += p.y;
        p = __builtin_amdgcn_cvt_pk_f32_fp8(u3, false); a0 += p.x; a1 += p.y;
        p = __builtin_amdgcn_cvt_pk_f32_fp8(u3, true);  a2 += p.x; a3 += p.y;
    }
    for (; e < e1; ++e) {
        unsigned u = x8[csr[e] * 32 + lane];
        f32x2 p;
        p = __builtin_amdgcn_cvt_pk_f32_fp8(u, false); a0 += p.x; a1 += p.y;
        p = __builtin_amdgcn_cvt_pk_f32_fp8(u, true);  a2 += p.x; a3 += p.y;
    }
    float w = invd[n] * FP8_INV_SCALE;
    uint2 o;
    o.x = (unsigned)f2bf(a0 * w) | ((unsigned)f2bf(a1 * w) << 16);
    o.y = (unsigned)f2bf(a2 * w) | ((unsigned)f2bf(a3 * w) << 16);
    ((uint2*)agg)[n * 32 + lane] = o;
}

// ---------------- MFMA GEMM: out = A1@W1 + A2@W2 + bias ; optional fused ydot ----------------
__global__ __launch_bounds__(256) void k_gemm(const ushort* __restrict__ A1,
                                              const ushort* __restrict__ A2,
                                              const uint4* __restrict__ Wf1,
                                              const uint4* __restrict__ Wf2,
                                              const float* __restrict__ bias,
                                              ushort* __restrict__ out,
                                              const float* __restrict__ Wout,
                                              const float* __restrict__ bout,
                                              float* __restrict__ y) {
    __shared__ uint4 sW[4096];  // 64 KB
    int t = threadIdx.x;
#pragma unroll
    for (int i = 0; i < 8; ++i) sW[t + i * 256] = Wf1[t + i * 256];
#pragma unroll
    for (int i = 0; i < 8; ++i) sW[2048 + t + i * 256] = Wf2[t + i * 256];
    __syncthreads();

    int w = t >> 6, lane = t & 63;
    int r0 = blockIdx.x * 128 + w * 32;
    int rowA = lane & 15, hi = lane >> 4;

    const ushort* Arow1 = A1 + (size_t)(r0 + rowA) * HID;
    const ushort* Arow2 = A2 + (size_t)(r0 + rowA) * HID;

    f32x4 acc[2][8];
#pragma unroll
    for (int rt = 0; rt < 2; ++rt)
#pragma unroll
        for (int c = 0; c < 8; ++c) acc[rt][c] = (f32x4){0.f, 0.f, 0.f, 0.f};

#pragma unroll
    for (int mat = 0; mat < 2; ++mat) {
        const ushort* Ab = mat ? Arow2 : Arow1;
        const uint4* sWm = &sW[mat * 2048];
#pragma unroll
        for (int s = 0; s < 4; ++s) {
            bf16x8 a0 = *(const bf16x8*)(Ab + s * 32 + hi * 8);
            bf16x8 a1 = *(const bf16x8*)(Ab + 16 * HID + s * 32 + hi * 8);
#pragma unroll
            for (int c = 0; c < 8; ++c) {
                bf16x8 b = *(const bf16x8*)&sWm[(c * 4 + s) * 64 + lane];
                acc[0][c] = __builtin_amdgcn_mfma_f32_16x16x32_bf16(a0, b, acc[0][c], 0, 0, 0);
                acc[1][c] = __builtin_amdgcn_mfma_f32_16x16x32_bf16(a1, b, acc[1][c], 0, 0, 0);
            }
        }
    }

    float ys[2][4];
    if (y) {
#pragma unroll
        for (int rt = 0; rt < 2; ++rt)
#pragma unroll
            for (int reg = 0; reg < 4; ++reg) ys[rt][reg] = 0.f;
    }

#pragma unroll
    for (int c = 0; c < 8; ++c) {
        int col = c * 16 + (lane & 15);
        float bv = bias[col];
        float wo = y ? Wout[col] : 0.f;
#pragma unroll
        for (int rt = 0; rt < 2; ++rt) {
#pragma unroll
            for (int reg = 0; reg < 4; ++reg) {
                float v = acc[rt][c][reg] + bv;
                int row = r0 + rt * 16 + hi * 4 + reg;
                out[(size_t)row * HID + col] = f2bf(v);
                if (y) ys[rt][reg] += v * wo;
            }
        }
    }

    if (y) {
        float b0 = bout[0];
#pragma unroll
        for (int rt = 0; rt < 2; ++rt) {
#pragma unroll
            for (int reg = 0; reg < 4; ++reg) {
                float s = ys[rt][reg];
                s += __shfl_xor(s, 1);
                s += __shfl_xor(s, 2);
                s += __shfl_xor(s, 4);
                s += __shfl_xor(s, 8);
                if ((lane & 15) == 0) {
                    int row = r0 + rt * 16 + hi * 4 + reg;
                    if (row < N_NODES) y[row] = s + b0;
                }
            }
        }
    }
}

// ---------------- softmax over gathered items (no max pass: |y| ~ 1e-3) ----------------
__global__ void k_sumexp(const float* __restrict__ y, const int* __restrict__ item,
                         float* __restrict__ redsum) {
    float s = 0.f;
    for (int i = blockIdx.x * blockDim.x + threadIdx.x; i < N_ITEMS; i += gridDim.x * blockDim.x)
        s += expf(y[item[i]]);
#pragma unroll
    for (int off = 32; off; off >>= 1) s += __shfl_down(s, off, 64);
    __shared__ float sm[4];
    int lane = threadIdx.x & 63, wave = threadIdx.x >> 6;
    if (lane == 0) sm[wave] = s;
    __syncthreads();
    if (threadIdx.x == 0) atomicAdd(redsum, sm[0] + sm[1] + sm[2] + sm[3]);
}

__global__ void k_out(const float* __restrict__ y, const int* __restrict__ item,
                      const float* __restrict__ redsum, const float* __restrict__ dprior,
                      float* __restrict__ out) {
    float inv_s = 1.0f / (*redsum);
    float pr = fmaxf(dprior[0], 0.f);
    for (int i = blockIdx.x * blockDim.x + threadIdx.x; i < N_ITEMS; i += gridDim.x * blockDim.x)
        out[i] = pr * expf(y[item[i]]) * inv_s;
}

extern "C" void kernel_launch(void* const* d_in, const int* in_sizes, int n_in,
                              void* d_out, int out_size, void* d_ws, size_t ws_size,
                              hipStream_t stream) {
    const int*   item  = (const int*)d_in[0];
    const int*   esrc  = (const int*)d_in[1];
    const int*   edst  = esrc + N_EDGES;
    const float* ue    = (const float*)d_in[2];
    const float* ie    = (const float*)d_in[3];
    const float* Wl1   = (const float*)d_in[4];
    const float* Wr1   = (const float*)d_in[5];
    const float* b1    = (const float*)d_in[6];
    const float* Wl2   = (const float*)d_in[7];
    const float* Wr2   = (const float*)d_in[8];
    const float* b2    = (const float*)d_in[9];
    const float* Wout  = (const float*)d_in[10];
    const float* bout  = (const float*)d_in[11];
    const float* dpri  = (const float*)d_in[12];
    float* out = (float*)d_out;

    // workspace layout (~98 MB)
    ushort*   xA   = (ushort*)d_ws;                       // MPAD*128 bf16
    ushort*   xB   = xA + (size_t)MPAD * HID;             // MPAD*128 bf16
    unsigned* x8A  = (unsigned*)(xB + (size_t)MPAD * HID);// MPAD*32 uints (fp8)
    unsigned* x8B  = x8A + (size_t)MPAD * 32;             // MPAD*32 uints
    uint4*    Wf   = (uint4*)(x8B + (size_t)MPAD * 32);   // 8192 uint4
    uint2*    part = (uint2*)(Wf + 8192);                 // N_EDGES uint2
    int*      csr  = (int*)(part + N_EDGES);              // N_EDGES
    int*      deg  = csr + N_EDGES;                       // MPAD
    float*    invd = (float*)(deg + MPAD);                // MPAD
    int*      rowp = (int*)(invd + MPAD);                 // 100104
    int*      parts_n = rowp + 100104;                    // 512
    int*      poff_n  = parts_n + 512;                    // 512
    int*      histc   = poff_n + 512;                     // NH
    int*      hists   = histc + NH;                       // NH
    int*      parts_h = hists + NH;                       // 512
    int*      poff_h  = parts_h + 512;                    // 512
    float*    y       = (float*)(poff_h + 512);           // N_NODES
    float*    redsum  = (float*)(y + N_NODES);

    hipMemsetAsync(deg, 0, N_NODES * sizeof(int), stream);
    hipMemsetAsync((void*)redsum, 0, 4, stream);

    // x build (+fp8 shadow) and W-fragment prep, fused
    k_build_x<<<2080, 256, 0, stream>>>(ue, ie, xA, x8A, Wl1, Wr1, Wl2, Wr2, Wf);

    // CSR build
    k_histdeg<<<NCOL, 512, 0, stream>>>(edst, deg, histc);
    k_scan1<<<SCAN_N, 256, 0, stream>>>(deg, rowp, parts_n, invd);
    k_scan2<<<1, 512, 0, stream>>>(parts_n, poff_n, SCAN_N);
    k_mscan<<<SCAN_N + SCAN_H, 256, 0, stream>>>(rowp, poff_n, histc, hists, parts_h);
    k_scan2<<<1, 512, 0, stream>>>(parts_h, poff_h, SCAN_H);
    k_gscan3<<<SCAN_H, 256, 0, stream>>>(hists, poff_h, NH);
    k_scatA<<<NCOL, 512, 0, stream>>>(esrc, edst, hists, part);
    k_scatB<<<NBKT, 512, 0, stream>>>(part, hists, rowp, csr);

    // layer 1
    k_agg<<<N_NODES / 8, 256, 0, stream>>>(x8A, rowp, csr, invd, xB);
    k_gemm<<<MPAD / 128, 256, 0, stream>>>(xB, xA, Wf, Wf + 2048, b1, xB,
                                           nullptr, nullptr, nullptr);
    k_enc8<<<2048, 256, 0, stream>>>(xB, x8B);
    // layer 2 (+fused ydot)
    k_agg<<<N_NODES / 8, 256, 0, stream>>>(x8B, rowp, csr, invd, xA);
    k_gemm<<<MPAD / 128, 256, 0, stream>>>(xA, xB, Wf + 4096, Wf + 6144, b2, xA,
                                           Wout, bout, y);

    k_sumexp<<<200, 256, 0, stream>>>(y, item, redsum);
    k_out<<<200, 256, 0, stream>>>(y, item, redsum, dpri, out);
}

// Round 6
// 310.508 us; speedup vs baseline: 2.7148x; 1.2272x over previous
//
#include <hip/hip_runtime.h>
#include <math.h>

#define N_USERS 50000
#define N_ITEMS 50000
#define N_NODES 100000
#define MPAD    100096   // padded rows: 782 blocks * 128
#define HID     128
#define N_EDGES 1600000

// CSR-build partition parameters
#define BKTW 512                  // nodes per dst-bucket
#define NBKT 196                  // ceil(N_NODES / BKTW)
#define NCOL 256                  // pass-A blocks
#define EPB  (N_EDGES / NCOL)     // 6250 edges per pass-A block
#define NH   (NBKT * NCOL)        // 50176 (bucket, block) counts
#define SCAN_H 196                // NH/256

#define FP8_SCALE     64.0f
#define FP8_INV_SCALE 0.015625f

typedef __attribute__((ext_vector_type(8))) short bf16x8;
typedef __attribute__((ext_vector_type(4))) float f32x4;
typedef __attribute__((ext_vector_type(2))) float f32x2;

static __device__ inline ushort f2bf(float f) {
    unsigned u = __float_as_uint(f);
    unsigned r = (u + 0x7fffu + ((u >> 16) & 1u)) >> 16;  // RNE
    return (ushort)r;
}
static __device__ inline float bflo(unsigned v) { return __uint_as_float(v << 16); }
static __device__ inline float bfhi(unsigned v) { return __uint_as_float(v & 0xffff0000u); }

// pack 4 floats -> 4 fp8 e4m3 bytes (pre-scaled)
static __device__ inline unsigned pk4_fp8(float v0, float v1, float v2, float v3) {
    unsigned w = __builtin_amdgcn_cvt_pk_fp8_f32(v0, v1, 0, false);
    w = __builtin_amdgcn_cvt_pk_fp8_f32(v2, v3, w, true);
    return w;
}

// ---------------- x = concat(user,item)->bf16 + fp8 shadow ; fused W prep ----------------
__global__ void k_build_x(const float* __restrict__ ue, const float* __restrict__ ie,
                          ushort* __restrict__ x, unsigned* __restrict__ x8,
                          const float* __restrict__ Wl1, const float* __restrict__ Wr1,
                          const float* __restrict__ Wl2, const float* __restrict__ Wr2,
                          uint4* __restrict__ Wf) {
    if (blockIdx.x >= 2048) {  // fused W-fragment prep
        int f = (blockIdx.x - 2048) * 256 + threadIdx.x;
        if (f >= 8192) return;
        int mat = f >> 11, r = f & 2047;
        int lane = r & 63, s = (r >> 6) & 3, c = r >> 8;
        const float* W = (mat == 0) ? Wl1 : (mat == 1) ? Wr1 : (mat == 2) ? Wl2 : Wr2;
        int col = c * 16 + (lane & 15);
        int k0 = s * 32 + (lane >> 4) * 8;
        ushort v[8];
#pragma unroll
        for (int j = 0; j < 8; ++j) v[j] = f2bf(W[(k0 + j) * HID + col]);
        uint4 o;
        o.x = (unsigned)v[0] | ((unsigned)v[1] << 16);
        o.y = (unsigned)v[2] | ((unsigned)v[3] << 16);
        o.z = (unsigned)v[4] | ((unsigned)v[5] << 16);
        o.w = (unsigned)v[6] | ((unsigned)v[7] << 16);
        Wf[f] = o;
        return;
    }
    const int total = N_NODES * HID / 4;
    const int uquads = N_USERS * HID / 4;
    for (int i = blockIdx.x * blockDim.x + threadIdx.x; i < total; i += 2048 * 256) {
        float4 v = (i < uquads) ? ((const float4*)ue)[i] : ((const float4*)ie)[i - uquads];
        uint2 o;
        o.x = (unsigned)f2bf(v.x) | ((unsigned)f2bf(v.y) << 16);
        o.y = (unsigned)f2bf(v.z) | ((unsigned)f2bf(v.w) << 16);
        ((uint2*)x)[i] = o;
        x8[i] = pk4_fp8(v.x * FP8_SCALE, v.y * FP8_SCALE, v.z * FP8_SCALE, v.w * FP8_SCALE);
    }
}

// ---------------- bf16 rows -> fp8 shadow (for layer-2 gather) ----------------
__global__ void k_enc8(const ushort* __restrict__ x, unsigned* __restrict__ x8) {
    const int total = MPAD * HID / 4;
    for (int i = blockIdx.x * blockDim.x + threadIdx.x; i < total; i += gridDim.x * blockDim.x) {
        uint2 u = ((const uint2*)x)[i];
        x8[i] = pk4_fp8(bflo(u.x) * FP8_SCALE, bfhi(u.x) * FP8_SCALE,
                        bflo(u.y) * FP8_SCALE, bfhi(u.y) * FP8_SCALE);
    }
}

// ---------------- pass A1: per-block bucket histogram (LDS only) ----------------
__global__ __launch_bounds__(512) void k_hist(const int* __restrict__ dst,
                                              int* __restrict__ histc) {
    __shared__ int lh[NBKT];
    int t = threadIdx.x, k = blockIdx.x;
    for (int i = t; i < NBKT; i += 512) lh[i] = 0;
    __syncthreads();
    int e0 = k * EPB;
    for (int e = e0 + t; e < e0 + EPB; e += 512)
        atomicAdd(&lh[dst[e] >> 9], 1);
    __syncthreads();
    for (int i = t; i < NBKT; i += 512) histc[i * NCOL + k] = lh[i];
}

// ---------------- hist scan (NH elements) ----------------
__global__ void k_gscan1(const int* __restrict__ in, int* __restrict__ out,
                         int* __restrict__ partials, int n) {
    __shared__ int s[256];
    int t = threadIdx.x;
    int i = blockIdx.x * 256 + t;
    int v = (i < n) ? in[i] : 0;
    s[t] = v;
    __syncthreads();
    for (int off = 1; off < 256; off <<= 1) {
        int add = (t >= off) ? s[t - off] : 0;
        __syncthreads();
        s[t] += add;
        __syncthreads();
    }
    if (i < n) out[i] = s[t] - v;
    if (t == 255) partials[blockIdx.x] = s[255];
}

__global__ void k_scan2(const int* __restrict__ partials, int* __restrict__ poff, int nparts) {
    __shared__ int s[512];
    int t = threadIdx.x;
    int v = (t < nparts) ? partials[t] : 0;
    s[t] = v;
    __syncthreads();
    for (int off = 1; off < 512; off <<= 1) {
        int add = (t >= off) ? s[t - off] : 0;
        __syncthreads();
        s[t] += add;
        __syncthreads();
    }
    poff[t] = s[t] - v;
}

__global__ void k_gscan3(int* __restrict__ out, const int* __restrict__ poff, int n) {
    int i = blockIdx.x * 256 + threadIdx.x;
    if (i < n) out[i] += poff[blockIdx.x];
}

// ---------------- pass A2: scatter packed (src | dst&511<<17) into partition ----------------
__global__ __launch_bounds__(512) void k_scatA(const int* __restrict__ src,
                                               const int* __restrict__ dst,
                                               const int* __restrict__ hists,
                                               unsigned* __restrict__ part) {
    __shared__ int cur[NBKT];
    int t = threadIdx.x, k = blockIdx.x;
    for (int i = t; i < NBKT; i += 512) cur[i] = hists[i * NCOL + k];
    __syncthreads();
    int e0 = k * EPB;
    for (int e = e0 + t; e < e0 + EPB; e += 512) {
        int s = src[e], d = dst[e];
        int pos = atomicAdd(&cur[d >> 9], 1);
        part[pos] = (unsigned)s | (((unsigned)d & 511u) << 17);
    }
}

// ---------------- pass B (fused): per-bucket deg count + local scan -> rowp/invd + csr fill ----------------
// Bucket b owns nodes [b*512,(b+1)*512); its csr window starts at p0 = hists[b*NCOL].
__global__ __launch_bounds__(512) void k_scatB(const unsigned* __restrict__ part,
                                               const int* __restrict__ hists,
                                               int* __restrict__ rowp,
                                               float* __restrict__ invd,
                                               int* __restrict__ csr) {
    __shared__ int ldeg[BKTW];
    __shared__ int s[BKTW];
    int t = threadIdx.x, b = blockIdx.x;
    int nb = b * BKTW;
    ldeg[t] = 0;
    __syncthreads();
    int p0 = hists[b * NCOL];
    int p1 = (b + 1 < NBKT) ? hists[(b + 1) * NCOL] : N_EDGES;
    for (int e = p0 + t; e < p1; e += 512)
        atomicAdd(&ldeg[part[e] >> 17], 1);
    __syncthreads();
    int v = ldeg[t];
    s[t] = v;
    __syncthreads();
    for (int off = 1; off < 512; off <<= 1) {
        int add = (t >= off) ? s[t - off] : 0;
        __syncthreads();
        s[t] += add;
        __syncthreads();
    }
    int base = p0 + s[t] - v;  // global exclusive row start for node nb+t
    int n = nb + t;
    if (n < N_NODES) {
        rowp[n] = base;
        invd[n] = 1.0f / (float)max(v, 1);
    }
    if (b == NBKT - 1 && t == 0) rowp[N_NODES] = N_EDGES;
    __syncthreads();
    ldeg[t] = base;  // reuse as write cursors
    __syncthreads();
    for (int e = p0 + t; e < p1; e += 512) {
        unsigned enc = part[e];
        int pos = atomicAdd(&ldeg[enc >> 17], 1);
        csr[pos] = (int)(enc & 0x1FFFFu);
    }
}

// ---------------- mean aggregation: fp8 gather, half-wave per node ----------------
__global__ __launch_bounds__(256) void k_agg(const unsigned* __restrict__ x8,
                                             const int* __restrict__ rowp,
                                             const int* __restrict__ csr,
                                             const float* __restrict__ invd,
                                             ushort* __restrict__ agg) {
    int half = threadIdx.x >> 5, lane = threadIdx.x & 31;
    int n = blockIdx.x * 8 + half;
    int e0 = rowp[n], e1 = rowp[n + 1];
    float a0 = 0.f, a1 = 0.f, a2 = 0.f, a3 = 0.f;
    int e = e0;
    for (; e + 3 < e1; e += 4) {
        int s0 = csr[e], s1 = csr[e + 1], s2 = csr[e + 2], s3 = csr[e + 3];
        unsigned u0 = x8[s0 * 32 + lane];
        unsigned u1 = x8[s1 * 32 + lane];
        unsigned u2 = x8[s2 * 32 + lane];
        unsigned u3 = x8[s3 * 32 + lane];
        f32x2 p;
        p = __builtin_amdgcn_cvt_pk_f32_fp8(u0, false); a0 += p.x; a1 += p.y;
        p = __builtin_amdgcn_cvt_pk_f32_fp8(u0, true);  a2 += p.x; a3 += p.y;
        p = __builtin_amdgcn_cvt_pk_f32_fp8(u1, false); a0 += p.x; a1 += p.y;
        p = __builtin_amdgcn_cvt_pk_f32_fp8(u1, true);  a2 += p.x; a3 += p.y;
        p = __builtin_amdgcn_cvt_pk_f32_fp8(u2, false); a0 += p.x; a1 += p.y;
        p = __builtin_amdgcn_cvt_pk_f32_fp8(u2, true);  a2 += p.x; a3 += p.y;
        p = __builtin_amdgcn_cvt_pk_f32_fp8(u3, false); a0 += p.x; a1 += p.y;
        p = __builtin_amdgcn_cvt_pk_f32_fp8(u3, true);  a2 += p.x; a3 += p.y;
    }
    for (; e < e1; ++e) {
        unsigned u = x8[csr[e] * 32 + lane];
        f32x2 p;
        p = __builtin_amdgcn_cvt_pk_f32_fp8(u, false); a0 += p.x; a1 += p.y;
        p = __builtin_amdgcn_cvt_pk_f32_fp8(u, true);  a2 += p.x; a3 += p.y;
    }
    float w = invd[n] * FP8_INV_SCALE;
    uint2 o;
    o.x = (unsigned)f2bf(a0 * w) | ((unsigned)f2bf(a1 * w) << 16);
    o.y = (unsigned)f2bf(a2 * w) | ((unsigned)f2bf(a3 * w) << 16);
    ((uint2*)agg)[n * 32 + lane] = o;
}

// ---------------- MFMA GEMM: out = A1@W1 + A2@W2 + bias ; optional fused ydot ----------------
__global__ __launch_bounds__(256) void k_gemm(const ushort* __restrict__ A1,
                                              const ushort* __restrict__ A2,
                                              const uint4* __restrict__ Wf1,
                                              const uint4* __restrict__ Wf2,
                                              const float* __restrict__ bias,
                                              ushort* __restrict__ out,
                                              const float* __restrict__ Wout,
                                              const float* __restrict__ bout,
                                              float* __restrict__ y) {
    __shared__ uint4 sW[4096];  // 64 KB
    int t = threadIdx.x;
#pragma unroll
    for (int i = 0; i < 8; ++i) sW[t + i * 256] = Wf1[t + i * 256];
#pragma unroll
    for (int i = 0; i < 8; ++i) sW[2048 + t + i * 256] = Wf2[t + i * 256];
    __syncthreads();

    int w = t >> 6, lane = t & 63;
    int r0 = blockIdx.x * 128 + w * 32;
    int rowA = lane & 15, hi = lane >> 4;

    const ushort* Arow1 = A1 + (size_t)(r0 + rowA) * HID;
    const ushort* Arow2 = A2 + (size_t)(r0 + rowA) * HID;

    f32x4 acc[2][8];
#pragma unroll
    for (int rt = 0; rt < 2; ++rt)
#pragma unroll
        for (int c = 0; c < 8; ++c) acc[rt][c] = (f32x4){0.f, 0.f, 0.f, 0.f};

#pragma unroll
    for (int mat = 0; mat < 2; ++mat) {
        const ushort* Ab = mat ? Arow2 : Arow1;
        const uint4* sWm = &sW[mat * 2048];
#pragma unroll
        for (int s = 0; s < 4; ++s) {
            bf16x8 a0 = *(const bf16x8*)(Ab + s * 32 + hi * 8);
            bf16x8 a1 = *(const bf16x8*)(Ab + 16 * HID + s * 32 + hi * 8);
#pragma unroll
            for (int c = 0; c < 8; ++c) {
                bf16x8 b = *(const bf16x8*)&sWm[(c * 4 + s) * 64 + lane];
                acc[0][c] = __builtin_amdgcn_mfma_f32_16x16x32_bf16(a0, b, acc[0][c], 0, 0, 0);
                acc[1][c] = __builtin_amdgcn_mfma_f32_16x16x32_bf16(a1, b, acc[1][c], 0, 0, 0);
            }
        }
    }

    float ys[2][4];
    if (y) {
#pragma unroll
        for (int rt = 0; rt < 2; ++rt)
#pragma unroll
            for (int reg = 0; reg < 4; ++reg) ys[rt][reg] = 0.f;
    }

#pragma unroll
    for (int c = 0; c < 8; ++c) {
        int col = c * 16 + (lane & 15);
        float bv = bias[col];
        float wo = y ? Wout[col] : 0.f;
#pragma unroll
        for (int rt = 0; rt < 2; ++rt) {
#pragma unroll
            for (int reg = 0; reg < 4; ++reg) {
                float v = acc[rt][c][reg] + bv;
                int row = r0 + rt * 16 + hi * 4 + reg;
                out[(size_t)row * HID + col] = f2bf(v);
                if (y) ys[rt][reg] += v * wo;
            }
        }
    }

    if (y) {
        float b0 = bout[0];
#pragma unroll
        for (int rt = 0; rt < 2; ++rt) {
#pragma unroll
            for (int reg = 0; reg < 4; ++reg) {
                float s = ys[rt][reg];
                s += __shfl_xor(s, 1);
                s += __shfl_xor(s, 2);
                s += __shfl_xor(s, 4);
                s += __shfl_xor(s, 8);
                if ((lane & 15) == 0) {
                    int row = r0 + rt * 16 + hi * 4 + reg;
                    if (row < N_NODES) y[row] = s + b0;
                }
            }
        }
    }
}

// ---------------- softmax over gathered items (no max pass: |y| ~ 1e-3) ----------------
__global__ void k_sumexp(const float* __restrict__ y, const int* __restrict__ item,
                         float* __restrict__ redsum) {
    float s = 0.f;
    for (int i = blockIdx.x * blockDim.x + threadIdx.x; i < N_ITEMS; i += gridDim.x * blockDim.x)
        s += expf(y[item[i]]);
#pragma unroll
    for (int off = 32; off; off >>= 1) s += __shfl_down(s, off, 64);
    __shared__ float sm[4];
    int lane = threadIdx.x & 63, wave = threadIdx.x >> 6;
    if (lane == 0) sm[wave] = s;
    __syncthreads();
    if (threadIdx.x == 0) atomicAdd(redsum, sm[0] + sm[1] + sm[2] + sm[3]);
}

__global__ void k_out(const float* __restrict__ y, const int* __restrict__ item,
                      const float* __restrict__ redsum, const float* __restrict__ dprior,
                      float* __restrict__ out) {
    float inv_s = 1.0f / (*redsum);
    float pr = fmaxf(dprior[0], 0.f);
    for (int i = blockIdx.x * blockDim.x + threadIdx.x; i < N_ITEMS; i += gridDim.x * blockDim.x)
        out[i] = pr * expf(y[item[i]]) * inv_s;
}

extern "C" void kernel_launch(void* const* d_in, const int* in_sizes, int n_in,
                              void* d_out, int out_size, void* d_ws, size_t ws_size,
                              hipStream_t stream) {
    const int*   item  = (const int*)d_in[0];
    const int*   esrc  = (const int*)d_in[1];
    const int*   edst  = esrc + N_EDGES;
    const float* ue    = (const float*)d_in[2];
    const float* ie    = (const float*)d_in[3];
    const float* Wl1   = (const float*)d_in[4];
    const float* Wr1   = (const float*)d_in[5];
    const float* b1    = (const float*)d_in[6];
    const float* Wl2   = (const float*)d_in[7];
    const float* Wr2   = (const float*)d_in[8];
    const float* b2    = (const float*)d_in[9];
    const float* Wout  = (const float*)d_in[10];
    const float* bout  = (const float*)d_in[11];
    const float* dpri  = (const float*)d_in[12];
    float* out = (float*)d_out;

    // workspace layout (~92 MB)
    ushort*   xA   = (ushort*)d_ws;                        // MPAD*128 bf16
    ushort*   xB   = xA + (size_t)MPAD * HID;              // MPAD*128 bf16
    unsigned* x8A  = (unsigned*)(xB + (size_t)MPAD * HID); // MPAD*32 uints (fp8)
    unsigned* x8B  = x8A + (size_t)MPAD * 32;              // MPAD*32 uints
    uint4*    Wf   = (uint4*)(x8B + (size_t)MPAD * 32);    // 8192 uint4
    unsigned* part = (unsigned*)(Wf + 8192);               // N_EDGES packed
    int*      csr  = (int*)(part + N_EDGES);               // N_EDGES
    float*    invd = (float*)(csr + N_EDGES);              // MPAD
    int*      rowp = (int*)(invd + MPAD);                  // 100104
    int*      histc   = rowp + 100104;                     // NH
    int*      hists   = histc + NH;                        // NH
    int*      parts_h = hists + NH;                        // 512
    int*      poff_h  = parts_h + 512;                     // 512
    float*    y       = (float*)(poff_h + 512);            // N_NODES
    float*    redsum  = (float*)(y + N_NODES);

    hipMemsetAsync((void*)redsum, 0, 4, stream);

    // x build (+fp8 shadow) and W-fragment prep, fused
    k_build_x<<<2080, 256, 0, stream>>>(ue, ie, xA, x8A, Wl1, Wr1, Wl2, Wr2, Wf);

    // CSR build: bucket histogram -> scan -> partition scatter -> fused fine pass
    k_hist<<<NCOL, 512, 0, stream>>>(edst, histc);
    k_gscan1<<<SCAN_H, 256, 0, stream>>>(histc, hists, parts_h, NH);
    k_scan2<<<1, 512, 0, stream>>>(parts_h, poff_h, SCAN_H);
    k_gscan3<<<SCAN_H, 256, 0, stream>>>(hists, poff_h, NH);
    k_scatA<<<NCOL, 512, 0, stream>>>(esrc, edst, hists, part);
    k_scatB<<<NBKT, 512, 0, stream>>>(part, hists, rowp, invd, csr);

    // layer 1
    k_agg<<<N_NODES / 8, 256, 0, stream>>>(x8A, rowp, csr, invd, xB);
    k_gemm<<<MPAD / 128, 256, 0, stream>>>(xB, xA, Wf, Wf + 2048, b1, xB,
                                           nullptr, nullptr, nullptr);
    k_enc8<<<2048, 256, 0, stream>>>(xB, x8B);
    // layer 2 (+fused ydot)
    k_agg<<<N_NODES / 8, 256, 0, stream>>>(x8B, rowp, csr, invd, xA);
    k_gemm<<<MPAD / 128, 256, 0, stream>>>(xA, xB, Wf + 4096, Wf + 6144, b2, xA,
                                           Wout, bout, y);

    k_sumexp<<<200, 256, 0, stream>>>(y, item, redsum);
    k_out<<<200, 256, 0, stream>>>(y, item, redsum, dpri, out);
}

// Round 7
// 206.655 us; speedup vs baseline: 4.0791x; 1.5025x over previous
//
#include <hip/hip_runtime.h>
#include <math.h>

#define N_USERS 50000
#define N_ITEMS 50000
#define N_NODES 100000
#define HID     128
#define N_EDGES 1600000

// dst-bucket partition parameters
#define BKTW 512                  // nodes per dst-bucket
#define NBKT 196                  // ceil(N_NODES / BKTW)
#define NCOL 256                  // pass-A blocks
#define EPB  (N_EDGES / NCOL)     // 6250 edges per pass-A block
#define NH   (NBKT * NCOL)        // 50176 (bucket, block) counts
#define SCAN_H 196                // NH/256

// ---------------- weight collapse: the whole net is linear ----------------
// y = invd*sum_nbr(z_l) + z_r ; z_l = invd*sum_nbr(p_l)+q_l+c_l ; z_r likewise(+c)
// p_* = x0 . u_* ; q_* = x0 . v_* ; u/v = W1 @ (W2 @ Wout)
__global__ void k_prep(const float* __restrict__ Wl1, const float* __restrict__ Wr1,
                       const float* __restrict__ b1,  const float* __restrict__ Wl2,
                       const float* __restrict__ Wr2, const float* __restrict__ b2,
                       const float* __restrict__ Wout, const float* __restrict__ bout,
                       float* __restrict__ cvec) {
    __shared__ float w2l[HID], w2r[HID];
    int t = threadIdx.x;
    if (t < 128) {
        float s = 0.f;
        for (int j = 0; j < HID; ++j) s += Wl2[t * HID + j] * Wout[j];
        w2l[t] = s;
    } else {
        int k = t - 128;
        float s = 0.f;
        for (int j = 0; j < HID; ++j) s += Wr2[k * HID + j] * Wout[j];
        w2r[k] = s;
    }
    __syncthreads();
    if (t < 128) {
        float sl = 0.f, sr = 0.f;
        for (int j = 0; j < HID; ++j) {
            float w = Wl1[t * HID + j];
            sl += w * w2l[j];
            sr += w * w2r[j];
        }
        cvec[t]       = sl;  // u_l
        cvec[256 + t] = sr;  // u_r
    } else {
        int k = t - 128;
        float sl = 0.f, sr = 0.f;
        for (int j = 0; j < HID; ++j) {
            float w = Wr1[k * HID + j];
            sl += w * w2l[j];
            sr += w * w2r[j];
        }
        cvec[128 + k] = sl;  // v_l
        cvec[384 + k] = sr;  // v_r
    }
    if (t == 0) {
        float cl = 0.f;
        for (int j = 0; j < HID; ++j) cl += b1[j] * w2l[j];
        cvec[512] = cl;                       // c_l (folded into q_l)
    }
    if (t == 1) {
        float cr = 0.f, c = 0.f;
        for (int j = 0; j < HID; ++j) { cr += b1[j] * w2r[j]; c += b2[j] * Wout[j]; }
        cvec[513] = cr + c + bout[0];         // c_r + c_total (folded into q_r)
    }
}

// ---------------- 4-way GEMV over embeddings: p/q scalars per node ----------------
// 16 lanes per node; one streaming pass over the 51.2 MB fp32 embeddings.
__global__ __launch_bounds__(256) void k_gemv(const float* __restrict__ ue,
                                              const float* __restrict__ ie,
                                              const float* __restrict__ cvec,
                                              float2* __restrict__ pq,
                                              float2* __restrict__ qq) {
    __shared__ __align__(16) float sc[516];
    int t = threadIdx.x;
    for (int i = t; i < 514; i += 256) sc[i] = cvec[i];
    __syncthreads();
    int g = t >> 4, l = t & 15;
    int n = blockIdx.x * 16 + g;
    const float* x = (n < N_USERS) ? (ue + (size_t)n * HID)
                                   : (ie + (size_t)(n - N_USERS) * HID);
    float4 xa = ((const float4*)x)[2 * l];
    float4 xb = ((const float4*)x)[2 * l + 1];
    const float4* u_l = (const float4*)&sc[0];
    const float4* v_l = (const float4*)&sc[128];
    const float4* u_r = (const float4*)&sc[256];
    const float4* v_r = (const float4*)&sc[384];
    float4 w0, w1;
    w0 = u_l[2 * l]; w1 = u_l[2 * l + 1];
    float pl = xa.x * w0.x + xa.y * w0.y + xa.z * w0.z + xa.w * w0.w
             + xb.x * w1.x + xb.y * w1.y + xb.z * w1.z + xb.w * w1.w;
    w0 = v_l[2 * l]; w1 = v_l[2 * l + 1];
    float ql = xa.x * w0.x + xa.y * w0.y + xa.z * w0.z + xa.w * w0.w
             + xb.x * w1.x + xb.y * w1.y + xb.z * w1.z + xb.w * w1.w;
    w0 = u_r[2 * l]; w1 = u_r[2 * l + 1];
    float pr = xa.x * w0.x + xa.y * w0.y + xa.z * w0.z + xa.w * w0.w
             + xb.x * w1.x + xb.y * w1.y + xb.z * w1.z + xb.w * w1.w;
    w0 = v_r[2 * l]; w1 = v_r[2 * l + 1];
    float qr = xa.x * w0.x + xa.y * w0.y + xa.z * w0.z + xa.w * w0.w
             + xb.x * w1.x + xb.y * w1.y + xb.z * w1.z + xb.w * w1.w;
#pragma unroll
    for (int m = 1; m < 16; m <<= 1) {
        pl += __shfl_xor(pl, m);
        ql += __shfl_xor(ql, m);
        pr += __shfl_xor(pr, m);
        qr += __shfl_xor(qr, m);
    }
    if (l == 0) {
        pq[n] = make_float2(pl, pr);
        qq[n] = make_float2(ql + sc[512], qr + sc[513]);
    }
}

// ---------------- pass A1: per-block bucket histogram (LDS only) ----------------
__global__ __launch_bounds__(512) void k_hist(const int* __restrict__ dst,
                                              int* __restrict__ histc) {
    __shared__ int lh[NBKT];
    int t = threadIdx.x, k = blockIdx.x;
    for (int i = t; i < NBKT; i += 512) lh[i] = 0;
    __syncthreads();
    int e0 = k * EPB;
    for (int e = e0 + t; e < e0 + EPB; e += 512)
        atomicAdd(&lh[dst[e] >> 9], 1);
    __syncthreads();
    for (int i = t; i < NBKT; i += 512) histc[i * NCOL + k] = lh[i];
}

// ---------------- hist scan (NH elements) ----------------
__global__ void k_gscan1(const int* __restrict__ in, int* __restrict__ out,
                         int* __restrict__ partials, int n) {
    __shared__ int s[256];
    int t = threadIdx.x;
    int i = blockIdx.x * 256 + t;
    int v = (i < n) ? in[i] : 0;
    s[t] = v;
    __syncthreads();
    for (int off = 1; off < 256; off <<= 1) {
        int add = (t >= off) ? s[t - off] : 0;
        __syncthreads();
        s[t] += add;
        __syncthreads();
    }
    if (i < n) out[i] = s[t] - v;
    if (t == 255) partials[blockIdx.x] = s[255];
}

__global__ void k_scan2(const int* __restrict__ partials, int* __restrict__ poff, int nparts) {
    __shared__ int s[512];
    int t = threadIdx.x;
    int v = (t < nparts) ? partials[t] : 0;
    s[t] = v;
    __syncthreads();
    for (int off = 1; off < 512; off <<= 1) {
        int add = (t >= off) ? s[t - off] : 0;
        __syncthreads();
        s[t] += add;
        __syncthreads();
    }
    poff[t] = s[t] - v;
}

__global__ void k_gscan3(int* __restrict__ out, const int* __restrict__ poff, int n) {
    int i = blockIdx.x * 256 + threadIdx.x;
    if (i < n) out[i] += poff[blockIdx.x];
}

// ---------------- pass A2: scatter packed (src | dstlocal<<17) into partition ----------------
__global__ __launch_bounds__(512) void k_scatA(const int* __restrict__ src,
                                               const int* __restrict__ dst,
                                               const int* __restrict__ hists,
                                               unsigned* __restrict__ part) {
    __shared__ int cur[NBKT];
    int t = threadIdx.x, k = blockIdx.x;
    for (int i = t; i < NBKT; i += 512) cur[i] = hists[i * NCOL + k];
    __syncthreads();
    int e0 = k * EPB;
    for (int e = e0 + t; e < e0 + EPB; e += 512) {
        int s = src[e], d = dst[e];
        int pos = atomicAdd(&cur[d >> 9], 1);
        part[pos] = (unsigned)s | (((unsigned)d & 511u) << 17);
    }
}

// ---------------- layer-1+2 scalar aggregation, round 1: z_l, z_r, invd ----------------
// bucket b owns nodes [b*512,(b+1)*512); LDS segment-sum of gathered p scalars.
__global__ __launch_bounds__(512) void k_aggs1(const unsigned* __restrict__ part,
                                               const int* __restrict__ hists,
                                               const float2* __restrict__ pq,
                                               const float2* __restrict__ qq,
                                               float* __restrict__ zl,
                                               float* __restrict__ zr,
                                               float* __restrict__ invd) {
    __shared__ float suml[BKTW], sumr[BKTW];
    __shared__ int cnt[BKTW];
    int t = threadIdx.x, b = blockIdx.x;
    suml[t] = 0.f; sumr[t] = 0.f; cnt[t] = 0;
    __syncthreads();
    int p0 = hists[b * NCOL];
    int p1 = (b + 1 < NBKT) ? hists[(b + 1) * NCOL] : N_EDGES;
    for (int e = p0 + t; e < p1; e += 512) {
        unsigned enc = part[e];
        float2 p = pq[enc & 0x1FFFFu];
        int dl = enc >> 17;
        atomicAdd(&suml[dl], p.x);
        atomicAdd(&sumr[dl], p.y);
        atomicAdd(&cnt[dl], 1);
    }
    __syncthreads();
    int n = b * BKTW + t;
    if (n < N_NODES) {
        float w = 1.f / (float)max(cnt[t], 1);
        float2 q = qq[n];
        zl[n] = suml[t] * w + q.x;
        zr[n] = sumr[t] * w + q.y;
        invd[n] = w;
    }
}

// ---------------- round 2: y = invd * sum_nbr(z_l) + z_r ----------------
__global__ __launch_bounds__(512) void k_aggs2(const unsigned* __restrict__ part,
                                               const int* __restrict__ hists,
                                               const float* __restrict__ zl,
                                               const float* __restrict__ zr,
                                               const float* __restrict__ invd,
                                               float* __restrict__ y) {
    __shared__ float sum[BKTW];
    int t = threadIdx.x, b = blockIdx.x;
    sum[t] = 0.f;
    __syncthreads();
    int p0 = hists[b * NCOL];
    int p1 = (b + 1 < NBKT) ? hists[(b + 1) * NCOL] : N_EDGES;
    for (int e = p0 + t; e < p1; e += 512) {
        unsigned enc = part[e];
        atomicAdd(&sum[enc >> 17], zl[enc & 0x1FFFFu]);
    }
    __syncthreads();
    int n = b * BKTW + t;
    if (n < N_NODES) y[n] = sum[t] * invd[n] + zr[n];
}

// ---------------- softmax over gathered items (no max pass: |y| ~ 1e-3) ----------------
__global__ void k_sumexp(const float* __restrict__ y, const int* __restrict__ item,
                         float* __restrict__ redsum) {
    float s = 0.f;
    for (int i = blockIdx.x * blockDim.x + threadIdx.x; i < N_ITEMS; i += gridDim.x * blockDim.x)
        s += expf(y[item[i]]);
#pragma unroll
    for (int off = 32; off; off >>= 1) s += __shfl_down(s, off, 64);
    __shared__ float sm[4];
    int lane = threadIdx.x & 63, wave = threadIdx.x >> 6;
    if (lane == 0) sm[wave] = s;
    __syncthreads();
    if (threadIdx.x == 0) atomicAdd(redsum, sm[0] + sm[1] + sm[2] + sm[3]);
}

__global__ void k_out(const float* __restrict__ y, const int* __restrict__ item,
                      const float* __restrict__ redsum, const float* __restrict__ dprior,
                      float* __restrict__ out) {
    float inv_s = 1.0f / (*redsum);
    float pr = fmaxf(dprior[0], 0.f);
    for (int i = blockIdx.x * blockDim.x + threadIdx.x; i < N_ITEMS; i += gridDim.x * blockDim.x)
        out[i] = pr * expf(y[item[i]]) * inv_s;
}

extern "C" void kernel_launch(void* const* d_in, const int* in_sizes, int n_in,
                              void* d_out, int out_size, void* d_ws, size_t ws_size,
                              hipStream_t stream) {
    const int*   item  = (const int*)d_in[0];
    const int*   esrc  = (const int*)d_in[1];
    const int*   edst  = esrc + N_EDGES;
    const float* ue    = (const float*)d_in[2];
    const float* ie    = (const float*)d_in[3];
    const float* Wl1   = (const float*)d_in[4];
    const float* Wr1   = (const float*)d_in[5];
    const float* b1    = (const float*)d_in[6];
    const float* Wl2   = (const float*)d_in[7];
    const float* Wr2   = (const float*)d_in[8];
    const float* b2    = (const float*)d_in[9];
    const float* Wout  = (const float*)d_in[10];
    const float* bout  = (const float*)d_in[11];
    const float* dpri  = (const float*)d_in[12];
    float* out = (float*)d_out;

    // workspace (~12 MB)
    unsigned* part = (unsigned*)d_ws;                 // N_EDGES packed (6.4 MB)
    float2*   pq   = (float2*)(part + N_EDGES);       // N_NODES (p_l, p_r)
    float2*   qq   = pq + N_NODES;                    // N_NODES (q_l+c_l, q_r+c_r+c)
    float*    zl   = (float*)(qq + N_NODES);          // N_NODES
    float*    zr   = zl + N_NODES;                    // N_NODES
    float*    invd = zr + N_NODES;                    // N_NODES
    float*    y    = invd + N_NODES;                  // N_NODES
    int*      histc   = (int*)(y + N_NODES);          // NH
    int*      hists   = histc + NH;                   // NH
    int*      parts_h = hists + NH;                   // 512
    int*      poff_h  = parts_h + 512;                // 512
    float*    cvec    = (float*)(poff_h + 512);       // 516
    float*    redsum  = cvec + 516;

    hipMemsetAsync((void*)redsum, 0, 4, stream);

    // weight collapse + per-node scalars
    k_prep<<<1, 256, 0, stream>>>(Wl1, Wr1, b1, Wl2, Wr2, b2, Wout, bout, cvec);
    k_gemv<<<N_NODES / 16, 256, 0, stream>>>(ue, ie, cvec, pq, qq);

    // dst-bucket partition of the edge list
    k_hist<<<NCOL, 512, 0, stream>>>(edst, histc);
    k_gscan1<<<SCAN_H, 256, 0, stream>>>(histc, hists, parts_h, NH);
    k_scan2<<<1, 512, 0, stream>>>(parts_h, poff_h, SCAN_H);
    k_gscan3<<<SCAN_H, 256, 0, stream>>>(hists, poff_h, NH);
    k_scatA<<<NCOL, 512, 0, stream>>>(esrc, edst, hists, part);

    // two scalar aggregation rounds
    k_aggs1<<<NBKT, 512, 0, stream>>>(part, hists, pq, qq, zl, zr, invd);
    k_aggs2<<<NBKT, 512, 0, stream>>>(part, hists, zl, zr, invd, y);

    // softmax over gathered items
    k_sumexp<<<200, 256, 0, stream>>>(y, item, redsum);
    k_out<<<200, 256, 0, stream>>>(y, item, redsum, dpri, out);
}